// Round 5
// baseline (321.101 us; speedup 1.0000x reference)
//
#include <hip/hip_runtime.h>
#include <math.h>

typedef __attribute__((ext_vector_type(4))) float f32x4;
typedef __attribute__((ext_vector_type(8))) _Float16 h16x8;
typedef __attribute__((ext_vector_type(4))) short s16x4;

__device__ inline unsigned short f2h(float f) {
    union { _Float16 h; unsigned short u; } v; v.h = (_Float16)f; return v.u;
}

__device__ inline void async16(const void* g, void* l) {
    __builtin_amdgcn_global_load_lds(
        (const __attribute__((address_space(1))) unsigned int*)g,
        (__attribute__((address_space(3))) unsigned int*)l, 16, 0, 0);
}

#define BM 256
#define BN 256
#define BK 64
#define NTHREADS 512

// LDS map (bytes), 128 KiB total:
//   buf d in {0,1}: base = d*65536
//   A half h: d*65536 + h*16384        (128 rows x 64 f16, XOR-swizzled)
//   B half h: d*65536 + 32768 + h*16384
// Swizzle (involution, 16B-granular): stored_off = row*128 + (cb ^ ((row&7)<<4))

__device__ inline void stage_half(const unsigned short* g, int row0, int kel, int K,
                                  unsigned ldsbase, char* smem, int tid) {
    const int rl  = tid >> 3;                          // 0..63 row within 64-row group
    const int scb = ((tid & 7) ^ (rl & 7)) << 4;       // swizzled source column byte
    char* wb = smem + ldsbase + (unsigned)((tid >> 6) << 10);   // wave-uniform
#pragma unroll
    for (int s = 0; s < 2; ++s) {
        long off = ((long)(row0 + s * 64 + rl) * K + kel) * 2 + scb;
        async16((const char*)g + off, wb + s * 8192);
    }
}

__device__ inline h16x8 ld_frag(const char* smem, unsigned base, int row, int kbyte) {
    unsigned off = base + (unsigned)(row * 128) + (unsigned)(kbyte ^ ((row & 7) << 4));
    return *(const h16x8*)(smem + off);
}

// C[M][N] = scale*(A[M][K] . B[N][K]^T) + bias ; A,B fp16 row-major pitch K.
// OM: 0 = fp32 out, 1 = fp16 out.
// Round-5 schedule: 4 phases/K-tile, 1 barrier/K-tile, A-frag register
// ping-pong so phase q+1's ds_reads fly during phase q's MFMA cluster.
template<int OM>
__global__ __launch_bounds__(NTHREADS, 2)
void gemm256(const unsigned short* __restrict__ A,
             const unsigned short* __restrict__ B,
             const float* __restrict__ bias,
             void* __restrict__ C, int N, int K,
             long sA, long sB, long sC, float scale)
{
    __shared__ __align__(16) char smem[131072];

    const int tid  = threadIdx.x;
    const int wv   = tid >> 6;
    const int lane = tid & 63;
    const int wr = wv >> 2, wc = wv & 3;       // 2M x 4N waves
    const int lrow = lane & 15;
    const int kq16 = (lane >> 4) * 16;         // k-quarter byte offset

    // bijective XCD-aware workgroup swizzle (m204 form)
    const long gx = gridDim.x, gy = gridDim.y;
    const long nwg = gx * gy * (long)gridDim.z;
    const long hw  = ((long)blockIdx.z * gy + blockIdx.y) * gx + blockIdx.x;
    const long qq = nwg >> 3, rr = nwg & 7;
    const long xcd = hw & 7, pos = hw >> 3;
    const long lg = (xcd < rr) ? xcd * (qq + 1) + pos
                               : rr * (qq + 1) + (xcd - rr) * qq + pos;
    const int bx = (int)(lg % gx);
    const long rem = lg / gx;
    const int by = (int)(rem % gy);
    const int bz = (int)(rem / gy);

    const int n0 = bx * BN;
    const int m0 = by * BM;

    const unsigned short* Ag = A + (long)bz * sA;
    const unsigned short* Bg = B + (long)bz * sB;

    const int NT = K / BK;

    auto stageA = [&](int t, int h) {
        stage_half(Ag, m0 + h * 128, t * BK, K,
                   (unsigned)(((t & 1) << 16) + (h << 14)), smem, tid);
    };
    auto stageB = [&](int t, int h) {
        stage_half(Bg, n0 + h * 128, t * BK, K,
                   (unsigned)(((t & 1) << 16) + 32768 + (h << 14)), smem, tid);
    };

    f32x4 acc[8][4];
#pragma unroll
    for (int i = 0; i < 8; ++i)
#pragma unroll
        for (int j = 0; j < 4; ++j) acc[i][j] = (f32x4){0.f, 0.f, 0.f, 0.f};

    const unsigned AbaseW = (unsigned)(wr * 16384);
    const unsigned BbaseW = (unsigned)(32768 + (wc >> 1) * 16384);
    const int brow0 = (wc & 1) * 64;

    // prologue: stage tile 0 into buf0, drain, barrier
    stageB(0, 0); stageB(0, 1); stageA(0, 0); stageA(0, 1);
    asm volatile("s_waitcnt vmcnt(0)" ::: "memory");
    __builtin_amdgcn_sched_barrier(0);
    __builtin_amdgcn_s_barrier();

    h16x8 bfr[4][2];
    h16x8 afr[2][2][2];   // [pingpong set][m-frag][k-slice]

    for (int t = 0; t < NT; ++t) {
        const unsigned buf = (unsigned)((t & 1) << 16);

        // tile-start reads: all 8 B-frags + A-quadrant 0 (into set 0)
#pragma unroll
        for (int j = 0; j < 4; ++j)
#pragma unroll
            for (int ks = 0; ks < 2; ++ks)
                bfr[j][ks] = ld_frag(smem, buf + BbaseW, brow0 + j * 16 + lrow, ks * 64 + kq16);
#pragma unroll
        for (int f = 0; f < 2; ++f)
#pragma unroll
            for (int ks = 0; ks < 2; ++ks)
                afr[0][f][ks] = ld_frag(smem, buf + AbaseW, f * 16 + lrow, ks * 64 + kq16);

        // stage next tile into the other buffer (its last reads retired
        // before the barrier that ended tile t-1 -> race-free)
        if (t + 1 < NT) {
            stageB(t + 1, 0); stageB(t + 1, 1);
            stageA(t + 1, 0); stageA(t + 1, 1);
        }

#pragma unroll
        for (int q = 0; q < 4; ++q) {
            asm volatile("s_waitcnt lgkmcnt(0)" ::: "memory");
            __builtin_amdgcn_sched_barrier(0);
            if (q < 3) {   // prefetch next A-quadrant into the other reg set
#pragma unroll
                for (int f = 0; f < 2; ++f)
#pragma unroll
                    for (int ks = 0; ks < 2; ++ks)
                        afr[(q + 1) & 1][f][ks] =
                            ld_frag(smem, buf + AbaseW, (q + 1) * 32 + f * 16 + lrow, ks * 64 + kq16);
            }
            __builtin_amdgcn_sched_barrier(0);
            __builtin_amdgcn_s_setprio(1);
#pragma unroll
            for (int f = 0; f < 2; ++f)
#pragma unroll
                for (int j = 0; j < 4; ++j)
#pragma unroll
                    for (int ks = 0; ks < 2; ++ks)
                        acc[2 * q + f][j] = __builtin_amdgcn_mfma_f32_16x16x32_f16(
                            afr[q & 1][f][ks], bfr[j][ks], acc[2 * q + f][j], 0, 0, 0);
            __builtin_amdgcn_s_setprio(0);
            __builtin_amdgcn_sched_barrier(0);
        }

        if (t + 1 < NT) { asm volatile("s_waitcnt vmcnt(0)" ::: "memory"); }
        __builtin_amdgcn_sched_barrier(0);
        __builtin_amdgcn_s_barrier();
    }

    // ---------------- epilogue ----------------
#pragma unroll
    for (int j = 0; j < 4; ++j) {
        const int col = n0 + wc * 64 + j * 16 + lrow;
        const float bb = bias ? bias[col] : 0.f;
#pragma unroll
        for (int mi = 0; mi < 8; ++mi) {
#pragma unroll
            for (int r = 0; r < 4; ++r) {
                const long row = m0 + wr * 128 + mi * 16 + (lane >> 4) * 4 + r;
                const float v = acc[mi][j][r] * scale + bb;
                const long idx = (long)bz * sC + row * (long)N + col;
                if constexpr (OM == 0) ((float*)C)[idx] = v;
                else                   ((unsigned short*)C)[idx] = f2h(v);
            }
        }
    }
}

// fp32 -> fp16 conversion, 4 elems/thread
__global__ __launch_bounds__(256)
void conv_f16(const float* __restrict__ in, unsigned short* __restrict__ out, int n)
{
    int i = (blockIdx.x * 256 + threadIdx.x) * 4;
    if (i >= n) return;
    float4 v = *(const float4*)(in + i);
    s16x4 o = {(short)f2h(v.x), (short)f2h(v.y), (short)f2h(v.z), (short)f2h(v.w)};
    *(s16x4*)(out + i) = o;
}

// values [16][1024][1024] f32 -> vT [16][1024][1024] fp16 (per-batch transpose)
__global__ __launch_bounds__(256)
void transpose_f16(const float* __restrict__ in, unsigned short* __restrict__ out)
{
    __shared__ float tile[32][33];
    const long base = (long)blockIdx.z * 1024 * 1024;
    const int h0 = blockIdx.x * 32, t0 = blockIdx.y * 32;
    for (int i = threadIdx.y; i < 32; i += 8)
        tile[i][threadIdx.x] = in[base + (long)(t0 + i) * 1024 + h0 + threadIdx.x];
    __syncthreads();
    for (int i = threadIdx.y; i < 32; i += 8)
        out[base + (long)(h0 + i) * 1024 + t0 + threadIdx.x] = f2h(tile[threadIdx.x][i]);
}

// row softmax: fp32 scores (1024/row) -> fp16 probs
__global__ __launch_bounds__(256)
void softmax_f16(const float* __restrict__ S, unsigned short* __restrict__ P)
{
    long row = blockIdx.x;
    const int tid = threadIdx.x;
    float4 v = *(const float4*)(S + row * 1024 + tid * 4);
    float m = fmaxf(fmaxf(v.x, v.y), fmaxf(v.z, v.w));
#pragma unroll
    for (int off = 1; off < 64; off <<= 1) m = fmaxf(m, __shfl_xor(m, off));
    __shared__ float redm[4];
    int wave = tid >> 6, lane = tid & 63;
    if (lane == 0) redm[wave] = m;
    __syncthreads();
    m = fmaxf(fmaxf(redm[0], redm[1]), fmaxf(redm[2], redm[3]));

    float e0 = expf(v.x - m), e1 = expf(v.y - m), e2 = expf(v.z - m), e3 = expf(v.w - m);
    float s = e0 + e1 + e2 + e3;
#pragma unroll
    for (int off = 1; off < 64; off <<= 1) s += __shfl_xor(s, off);
    __shared__ float reds[4];
    if (lane == 0) reds[wave] = s;
    __syncthreads();
    s = reds[0] + reds[1] + reds[2] + reds[3];
    float inv = 1.f / s;
    s16x4 o = {(short)f2h(e0 * inv), (short)f2h(e1 * inv),
               (short)f2h(e2 * inv), (short)f2h(e3 * inv)};
    *(s16x4*)(P + row * 1024 + tid * 4) = o;
}

extern "C" void kernel_launch(void* const* d_in, const int* in_sizes, int n_in,
                              void* d_out, int out_size, void* d_ws, size_t ws_size,
                              hipStream_t stream)
{
    const float* query  = (const float*)d_in[0];
    const float* keys   = (const float*)d_in[1];
    const float* values = (const float*)d_in[2];
    const float* Wq     = (const float*)d_in[3];
    const float* bq     = (const float*)d_in[4];
    const float* Wk     = (const float*)d_in[5];
    const float* bk     = (const float*)d_in[6];
    const float* Wo     = (const float*)d_in[7];
    const float* bo     = (const float*)d_in[8];

    const int  T = 1024, H = 1024;
    const long NE = 16384L * 1024;   // B*T*H
    const long NW = 1024L * 1024;    // H*H

    size_t need = (size_t)(NE * 5 + NW * 3) * sizeof(unsigned short);
    if (ws_size < need) return;

    unsigned short* ws  = (unsigned short*)d_ws;
    unsigned short* Xq  = ws;             // query fp16   (dead after stage 1)
    unsigned short* Xk  = Xq + NE;        // keys fp16    (dead after stage 2)
    unsigned short* qf  = Xk + NE;
    unsigned short* kf  = qf + NE;
    unsigned short* vT  = kf + NE;
    unsigned short* Wqh = vT + NE;
    unsigned short* Wkh = Wqh + NW;
    unsigned short* Woh = Wkh + NW;
    unsigned short* attn = Xq;            // alias: probs
    unsigned short* ctx  = Xk;            // alias: context
    float* scores = (float*)d_out;        // d_out doubles as fp32 scratch

    // ---- prep: fp32 -> fp16 ----
    conv_f16<<<16384, 256, 0, stream>>>(query, Xq, (int)NE);
    conv_f16<<<16384, 256, 0, stream>>>(keys,  Xk, (int)NE);
    conv_f16<<<1024,  256, 0, stream>>>(Wq, Wqh, (int)NW);
    conv_f16<<<1024,  256, 0, stream>>>(Wk, Wkh, (int)NW);
    conv_f16<<<1024,  256, 0, stream>>>(Wo, Woh, (int)NW);
    transpose_f16<<<dim3(32, 32, 16), dim3(32, 8), 0, stream>>>(values, vT);

    // 1. q = query @ Wq^T + bq   (fp16 out)   grid 4x64 = 256 WG
    gemm256<1><<<dim3(4, 64, 1), NTHREADS, 0, stream>>>(
        Xq, Wqh, bq, qf, H, H, 0, 0, 0, 1.f);
    // 2. k = keys @ Wk^T + bk
    gemm256<1><<<dim3(4, 64, 1), NTHREADS, 0, stream>>>(
        Xk, Wkh, bk, kf, H, H, 0, 0, 0, 1.f);
    // 3. scores = q @ k^T (batched, fp32 out into d_out)  grid 4x4x16 = 256 WG
    gemm256<0><<<dim3(4, 4, 16), NTHREADS, 0, stream>>>(
        qf, kf, nullptr, scores, T, H, (long)T * H, (long)T * H, (long)T * T, 1.f);
    // 4. softmax -> fp16 probs
    softmax_f16<<<16384, 256, 0, stream>>>(scores, attn);
    // 5. ctx = attn @ vT^T / 32 (batched, fp16 out)
    gemm256<1><<<dim3(4, 4, 16), NTHREADS, 0, stream>>>(
        attn, vT, nullptr, ctx, H, T, (long)T * T, (long)T * H, (long)T * H, 1.f / 32.f);
    // 6. out = ctx @ Wo^T + bo (fp32 out)
    gemm256<0><<<dim3(4, 64, 1), NTHREADS, 0, stream>>>(
        ctx, Woh, bo, d_out, H, H, 0, 0, 0, 1.f);
}

// Round 6
// 320.300 us; speedup vs baseline: 1.0025x; 1.0025x over previous
//
#include <hip/hip_runtime.h>
#include <math.h>

typedef __attribute__((ext_vector_type(4))) float f32x4;
typedef __attribute__((ext_vector_type(8))) _Float16 h16x8;
typedef __attribute__((ext_vector_type(4))) short s16x4;

__device__ inline unsigned short f2h(float f) {
    union { _Float16 h; unsigned short u; } v; v.h = (_Float16)f; return v.u;
}
__device__ inline float h2f(unsigned short u) {
    union { unsigned short u; _Float16 h; } v; v.u = u; return (float)v.h;
}

__device__ inline void async16(const void* g, void* l) {
    __builtin_amdgcn_global_load_lds(
        (const __attribute__((address_space(1))) unsigned int*)g,
        (__attribute__((address_space(3))) unsigned int*)l, 16, 0, 0);
}

#define BM 256
#define BN 256
#define BK 64
#define NTHREADS 512

// LDS map (bytes), 128 KiB: buf d: d*65536; A half h: +h*16384; B half h: +32768+h*16384
// Swizzle (involution, 16B slots): stored = row*128 + (cb ^ ((row&7)<<4))

__device__ inline void stage_half(const unsigned short* g, int row0, int kel, int K,
                                  unsigned ldsbase, char* smem, int tid) {
    const int rl  = tid >> 3;
    const int scb = ((tid & 7) ^ (rl & 7)) << 4;
    char* wb = smem + ldsbase + (unsigned)((tid >> 6) << 10);
#pragma unroll
    for (int s = 0; s < 2; ++s) {
        long off = ((long)(row0 + s * 64 + rl) * K + kel) * 2 + scb;
        async16((const char*)g + off, wb + s * 8192);
    }
}

__device__ inline h16x8 ld_frag(const char* smem, unsigned base, int row, int kbyte) {
    unsigned off = base + (unsigned)(row * 128) + (unsigned)(kbyte ^ ((row & 7) << 4));
    return *(const h16x8*)(smem + off);
}

// bijective XCD-aware workgroup swizzle (m204 form)
__device__ inline void xcd_swizzle(int& bx, int& by, int& bz) {
    const long gx = gridDim.x, gy = gridDim.y;
    const long nwg = gx * gy * (long)gridDim.z;
    const long hw  = ((long)blockIdx.z * gy + blockIdx.y) * gx + blockIdx.x;
    const long qq = nwg >> 3, rr = nwg & 7;
    const long xcd = hw & 7, pos = hw >> 3;
    const long lg = (xcd < rr) ? xcd * (qq + 1) + pos
                               : rr * (qq + 1) + (xcd - rr) * qq + pos;
    bx = (int)(lg % gx);
    const long rem = lg / gx;
    by = (int)(rem % gy);
    bz = (int)(rem / gy);
}

// ---------------- AMODE0: both operands f16 via global_load_lds ----------------
// C = scale*(A . B^T) + bias. OM: 0 = f32 out, 1 = f16 out. 8-phase r4 schedule.
template<int OM>
__global__ __launch_bounds__(NTHREADS, 2)
void gemm256(const unsigned short* __restrict__ A,
             const unsigned short* __restrict__ B,
             const float* __restrict__ bias,
             void* __restrict__ C, int N, int K,
             long sA, long sB, long sC, float scale)
{
    __shared__ __align__(16) char smem[131072];

    const int tid  = threadIdx.x;
    const int wv   = tid >> 6;
    const int lane = tid & 63;
    const int wr = wv >> 2, wc = wv & 3;
    const int lrow = lane & 15;
    const int kq16 = (lane >> 4) * 16;

    int bx, by, bz; xcd_swizzle(bx, by, bz);
    const int n0 = bx * BN;
    const int m0 = by * BM;

    const unsigned short* Ag = A + (long)bz * sA;
    const unsigned short* Bg = B + (long)bz * sB;
    const int NT = K / BK;

    auto stageA = [&](int t, int h) {
        stage_half(Ag, m0 + h * 128, t * BK, K,
                   (unsigned)(((t & 1) << 16) + (h << 14)), smem, tid);
    };
    auto stageB = [&](int t, int h) {
        stage_half(Bg, n0 + h * 128, t * BK, K,
                   (unsigned)(((t & 1) << 16) + 32768 + (h << 14)), smem, tid);
    };

    f32x4 acc[8][4];
#pragma unroll
    for (int i = 0; i < 8; ++i)
#pragma unroll
        for (int j = 0; j < 4; ++j) acc[i][j] = (f32x4){0.f, 0.f, 0.f, 0.f};

    const unsigned AbaseW = (unsigned)(wr * 16384);
    const unsigned BbaseW = (unsigned)(32768 + (wc >> 1) * 16384);
    const int brow0 = (wc & 1) * 64;

    stageB(0, 0); stageB(0, 1); stageA(0, 0); stageA(0, 1); stageB(1, 0); stageB(1, 1);
    asm volatile("s_waitcnt vmcnt(4)" ::: "memory");
    __builtin_amdgcn_s_barrier();

    h16x8 bfr[4][2], afr[2][2];

    for (int i = 0; i < NT / 2; ++i) {
        const int t1 = 2 * i + 1, t2 = 2 * i + 2, t3 = 2 * i + 3;
#pragma unroll
        for (int half = 0; half < 2; ++half) {
            const unsigned hb = half ? 65536u : 0u;
#pragma unroll
            for (int q = 0; q < 4; ++q) {
                if (q == 0) {
#pragma unroll
                    for (int j = 0; j < 4; ++j)
#pragma unroll
                        for (int ks = 0; ks < 2; ++ks)
                            bfr[j][ks] = ld_frag(smem, hb + BbaseW, brow0 + j * 16 + lrow, ks * 64 + kq16);
                }
#pragma unroll
                for (int f = 0; f < 2; ++f)
#pragma unroll
                    for (int ks = 0; ks < 2; ++ks)
                        afr[f][ks] = ld_frag(smem, hb + AbaseW, q * 32 + f * 16 + lrow, ks * 64 + kq16);
                if (half == 0) {
                    if (q == 0)      stageA(t1, 0);
                    else if (q == 1) stageA(t1, 1);
                    else if (q == 2) { if (t2 < NT) stageB(t2, 0); }
                    else             { if (t2 < NT) stageB(t2, 1); }
                } else {
                    if (q == 0)      { if (t2 < NT) stageA(t2, 0); }
                    else if (q == 1) { if (t2 < NT) stageA(t2, 1); }
                    else if (q == 2) { if (t3 < NT) stageB(t3, 0); }
                    else             { if (t3 < NT) stageB(t3, 1); }
                }

                __builtin_amdgcn_s_barrier();
                asm volatile("s_waitcnt lgkmcnt(0)" ::: "memory");
                __builtin_amdgcn_sched_barrier(0);
                __builtin_amdgcn_s_setprio(1);
#pragma unroll
                for (int ks = 0; ks < 2; ++ks)
#pragma unroll
                    for (int f = 0; f < 2; ++f)
#pragma unroll
                        for (int j = 0; j < 4; ++j)
                            acc[2 * q + f][j] = __builtin_amdgcn_mfma_f32_16x16x32_f16(
                                afr[f][ks], bfr[j][ks], acc[2 * q + f][j], 0, 0, 0);
                __builtin_amdgcn_s_setprio(0);
                if (q == 3) {
                    const int tn = half ? t3 : t2;
                    if (tn < NT) { asm volatile("s_waitcnt vmcnt(4)" ::: "memory"); }
                    else         { asm volatile("s_waitcnt vmcnt(0)" ::: "memory"); }
                }
                __builtin_amdgcn_s_barrier();
            }
        }
    }

#pragma unroll
    for (int j = 0; j < 4; ++j) {
        const int col = n0 + wc * 64 + j * 16 + lrow;
        const float bb = bias ? bias[col] : 0.f;
#pragma unroll
        for (int mi = 0; mi < 8; ++mi) {
#pragma unroll
            for (int r = 0; r < 4; ++r) {
                const long row = m0 + wr * 128 + mi * 16 + (lane >> 4) * 4 + r;
                const float v = acc[mi][j][r] * scale + bb;
                const long idx = (long)bz * sC + row * (long)N + col;
                if constexpr (OM == 0) ((float*)C)[idx] = v;
                else                   ((unsigned short*)C)[idx] = f2h(v);
            }
        }
    }
}

// ---------------- f32-A variant (fused convert): proj GEMMs ----------------
// A fp32 [M][K]; B f16 [N][K]; C f16 = A.B^T + bias. 4 phases/tile.
__global__ __launch_bounds__(NTHREADS, 2)
void gemm256_f32a(const float* __restrict__ A,
                  const unsigned short* __restrict__ B,
                  const float* __restrict__ bias,
                  unsigned short* __restrict__ C, int N, int K)
{
    __shared__ __align__(16) char smem[131072];

    const int tid  = threadIdx.x;
    const int wv   = tid >> 6;
    const int lane = tid & 63;
    const int wr = wv >> 2, wc = wv & 3;
    const int lrow = lane & 15;
    const int kq16 = (lane >> 4) * 16;

    int bx, by, bz; xcd_swizzle(bx, by, bz);
    const int n0 = bx * BN;
    const int m0 = by * BM;
    const int NT = K / BK;

    const int fm  = (tid >> 4);        // row handled per l-step base (f>>4 with f=l*512+tid)
    const int c4  = tid & 15;          // 16B-f32 chunk index within row (0..15)

    auto loadA = [&](int t, float4* r) {
#pragma unroll
        for (int l = 0; l < 8; ++l) {
            int m = fm + l * 32;
            r[l] = *(const float4*)(A + (long)(m0 + m) * K + t * BK + c4 * 4);
        }
    };
    auto writeA = [&](int t, const float4* r) {
        const unsigned buf = (unsigned)((t & 1) << 16);
#pragma unroll
        for (int l = 0; l < 8; ++l) {
            int m = fm + l * 32;
            int h = m >> 7, ri = m & 127;
            unsigned addr = buf + (unsigned)(h * 16384 + ri * 128 +
                              ((((c4 >> 1) ^ (ri & 7))) << 4) + ((c4 & 1) << 3));
            float4 v = r[l];
            s16x4 hv = {(short)f2h(v.x), (short)f2h(v.y), (short)f2h(v.z), (short)f2h(v.w)};
            *(s16x4*)(smem + addr) = hv;
        }
    };
    auto stageB = [&](int t, int h) {
        stage_half(B, n0 + h * 128, t * BK, K,
                   (unsigned)(((t & 1) << 16) + 32768 + (h << 14)), smem, tid);
    };

    f32x4 acc[8][4];
#pragma unroll
    for (int i = 0; i < 8; ++i)
#pragma unroll
        for (int j = 0; j < 4; ++j) acc[i][j] = (f32x4){0.f, 0.f, 0.f, 0.f};

    const unsigned AbaseW = (unsigned)(wr * 16384);
    const unsigned BbaseW = (unsigned)(32768 + (wc >> 1) * 16384);
    const int brow0 = (wc & 1) * 64;

    float4 a_pre[8];
    // prologue: tile 0
    loadA(0, a_pre);
    asm volatile("s_waitcnt vmcnt(0)" ::: "memory");
    writeA(0, a_pre);
    stageB(0, 0); stageB(0, 1);
    if (NT > 1) loadA(1, a_pre);
    asm volatile("s_waitcnt lgkmcnt(0) vmcnt(8)" ::: "memory");   // ds_writes + B(0) done
    __builtin_amdgcn_s_barrier();

    h16x8 bfr[4][2], afr[2][2];

    for (int t = 0; t < NT; ++t) {
        const unsigned buf = (unsigned)((t & 1) << 16);
        if (t > 0) {
            writeA(t, a_pre);   // regs loaded during t-1, vmcnt(0) drained at t-1 q3
            asm volatile("s_waitcnt lgkmcnt(0)" ::: "memory");
            __builtin_amdgcn_s_barrier();
        }
#pragma unroll
        for (int q = 0; q < 4; ++q) {
            if (q == 0) {
#pragma unroll
                for (int j = 0; j < 4; ++j)
#pragma unroll
                    for (int ks = 0; ks < 2; ++ks)
                        bfr[j][ks] = ld_frag(smem, buf + BbaseW, brow0 + j * 16 + lrow, ks * 64 + kq16);
            }
#pragma unroll
            for (int f = 0; f < 2; ++f)
#pragma unroll
                for (int ks = 0; ks < 2; ++ks)
                    afr[f][ks] = ld_frag(smem, buf + AbaseW, q * 32 + f * 16 + lrow, ks * 64 + kq16);
            if (t + 1 < NT) {
                if (q == 0) { stageB(t + 1, 0); loadA(t + 1, a_pre); }
                else if (q == 1) stageB(t + 1, 1);
            }
            __builtin_amdgcn_s_barrier();
            asm volatile("s_waitcnt lgkmcnt(0)" ::: "memory");
            __builtin_amdgcn_sched_barrier(0);
            __builtin_amdgcn_s_setprio(1);
#pragma unroll
            for (int ks = 0; ks < 2; ++ks)
#pragma unroll
                for (int f = 0; f < 2; ++f)
#pragma unroll
                    for (int j = 0; j < 4; ++j)
                        acc[2 * q + f][j] = __builtin_amdgcn_mfma_f32_16x16x32_f16(
                            afr[f][ks], bfr[j][ks], acc[2 * q + f][j], 0, 0, 0);
            __builtin_amdgcn_s_setprio(0);
            if (q == 3) { asm volatile("s_waitcnt vmcnt(0)" ::: "memory"); }
            __builtin_amdgcn_s_barrier();
        }
    }

#pragma unroll
    for (int j = 0; j < 4; ++j) {
        const int col = n0 + wc * 64 + j * 16 + lrow;
        const float bb = bias[col];
#pragma unroll
        for (int mi = 0; mi < 8; ++mi) {
#pragma unroll
            for (int r = 0; r < 4; ++r) {
                const long row = m0 + wr * 128 + mi * 16 + (lane >> 4) * 4 + r;
                C[row * (long)N + col] = f2h(acc[mi][j][r] + bb);
            }
        }
    }
}

// fp32 -> fp16 conversion (weights)
__global__ __launch_bounds__(256)
void conv_f16(const float* __restrict__ in, unsigned short* __restrict__ out, int n)
{
    int i = (blockIdx.x * 256 + threadIdx.x) * 4;
    if (i >= n) return;
    float4 v = *(const float4*)(in + i);
    s16x4 o = {(short)f2h(v.x), (short)f2h(v.y), (short)f2h(v.z), (short)f2h(v.w)};
    *(s16x4*)(out + i) = o;
}

// values [16][1024][1024] f32 -> vT f16 (per-batch transpose)
__global__ __launch_bounds__(256)
void transpose_f16(const float* __restrict__ in, unsigned short* __restrict__ out)
{
    __shared__ float tile[32][33];
    const long base = (long)blockIdx.z * 1024 * 1024;
    const int h0 = blockIdx.x * 32, t0 = blockIdx.y * 32;
    for (int i = threadIdx.y; i < 32; i += 8)
        tile[i][threadIdx.x] = in[base + (long)(t0 + i) * 1024 + h0 + threadIdx.x];
    __syncthreads();
    for (int i = threadIdx.y; i < 32; i += 8)
        out[base + (long)(h0 + i) * 1024 + t0 + threadIdx.x] = f2h(tile[threadIdx.x][i]);
}

// in-place row softmax on fp16 logits (1024/row)
__global__ __launch_bounds__(256)
void softmax_ip(unsigned short* __restrict__ S)
{
    long row = blockIdx.x;
    const int tid = threadIdx.x;
    s16x4 raw = *(s16x4*)(S + row * 1024 + tid * 4);
    float v0 = h2f((unsigned short)raw[0]), v1 = h2f((unsigned short)raw[1]);
    float v2 = h2f((unsigned short)raw[2]), v3 = h2f((unsigned short)raw[3]);
    float m = fmaxf(fmaxf(v0, v1), fmaxf(v2, v3));
#pragma unroll
    for (int off = 1; off < 64; off <<= 1) m = fmaxf(m, __shfl_xor(m, off));
    __shared__ float redm[4];
    int wave = tid >> 6, lane = tid & 63;
    if (lane == 0) redm[wave] = m;
    __syncthreads();
    m = fmaxf(fmaxf(redm[0], redm[1]), fmaxf(redm[2], redm[3]));

    float e0 = expf(v0 - m), e1 = expf(v1 - m), e2 = expf(v2 - m), e3 = expf(v3 - m);
    float s = e0 + e1 + e2 + e3;
#pragma unroll
    for (int off = 1; off < 64; off <<= 1) s += __shfl_xor(s, off);
    __shared__ float reds[4];
    if (lane == 0) reds[wave] = s;
    __syncthreads();
    s = reds[0] + reds[1] + reds[2] + reds[3];
    float inv = 1.f / s;
    s16x4 o = {(short)f2h(e0 * inv), (short)f2h(e1 * inv),
               (short)f2h(e2 * inv), (short)f2h(e3 * inv)};
    *(s16x4*)(S + row * 1024 + tid * 4) = o;
}

extern "C" void kernel_launch(void* const* d_in, const int* in_sizes, int n_in,
                              void* d_out, int out_size, void* d_ws, size_t ws_size,
                              hipStream_t stream)
{
    const float* query  = (const float*)d_in[0];
    const float* keys   = (const float*)d_in[1];
    const float* values = (const float*)d_in[2];
    const float* Wq     = (const float*)d_in[3];
    const float* bq     = (const float*)d_in[4];
    const float* Wk     = (const float*)d_in[5];
    const float* bk     = (const float*)d_in[6];
    const float* Wo     = (const float*)d_in[7];
    const float* bo     = (const float*)d_in[8];

    const int  T = 1024, H = 1024;
    const long NE = 16384L * 1024;   // B*T*H (== B*T*T)
    const long NW = 1024L * 1024;

    size_t need = (size_t)(NE * 5 + NW * 3) * sizeof(unsigned short);
    if (ws_size < need) return;

    unsigned short* ws  = (unsigned short*)d_ws;
    unsigned short* qf  = ws;
    unsigned short* kf  = qf + NE;
    unsigned short* vT  = kf + NE;
    unsigned short* sc  = vT + NE;        // fp16 scores -> probs (in-place)
    unsigned short* ctx = sc + NE;
    unsigned short* Wqh = ctx + NE;
    unsigned short* Wkh = Wqh + NW;
    unsigned short* Woh = Wkh + NW;

    // prep: weights fp16, values transpose
    conv_f16<<<1024, 256, 0, stream>>>(Wq, Wqh, (int)NW);
    conv_f16<<<1024, 256, 0, stream>>>(Wk, Wkh, (int)NW);
    conv_f16<<<1024, 256, 0, stream>>>(Wo, Woh, (int)NW);
    transpose_f16<<<dim3(32, 32, 16), dim3(32, 8), 0, stream>>>(values, vT);

    // 1. q = query @ Wq^T + bq   (fused f32->f16 A)
    gemm256_f32a<<<dim3(4, 64, 1), NTHREADS, 0, stream>>>(query, Wqh, bq, qf, H, H);
    // 2. k = keys @ Wk^T + bk
    gemm256_f32a<<<dim3(4, 64, 1), NTHREADS, 0, stream>>>(keys, Wkh, bk, kf, H, H);
    // 3. scores = q @ k^T (batched, fp16 out)
    gemm256<1><<<dim3(4, 4, 16), NTHREADS, 0, stream>>>(
        qf, kf, nullptr, sc, T, H, (long)T * H, (long)T * H, (long)T * T, 1.f);
    // 4. softmax in place (fp16 -> fp16)
    softmax_ip<<<16384, 256, 0, stream>>>(sc);
    // 5. ctx = attn @ vT^T / 32 (batched, fp16 out)
    gemm256<1><<<dim3(4, 4, 16), NTHREADS, 0, stream>>>(
        sc, vT, nullptr, ctx, H, T, (long)T * T, (long)T * H, (long)T * H, 1.f / 32.f);
    // 6. out = ctx @ Wo^T + bo (fp32 out)
    gemm256<0><<<dim3(4, 64, 1), NTHREADS, 0, stream>>>(
        ctx, Woh, bo, d_out, H, H, 0, 0, 0, 1.f);
}

// Round 7
// 312.711 us; speedup vs baseline: 1.0268x; 1.0243x over previous
//
#include <hip/hip_runtime.h>
#include <math.h>

typedef __attribute__((ext_vector_type(4))) float f32x4;
typedef __attribute__((ext_vector_type(8))) _Float16 h16x8;
typedef __attribute__((ext_vector_type(4))) short s16x4;

__device__ inline unsigned short f2h(float f) {
    union { _Float16 h; unsigned short u; } v; v.h = (_Float16)f; return v.u;
}
__device__ inline float h2f(unsigned short u) {
    union { unsigned short u; _Float16 h; } v; v.u = u; return (float)v.h;
}

__device__ inline void async16(const void* g, void* l) {
    __builtin_amdgcn_global_load_lds(
        (const __attribute__((address_space(1))) unsigned int*)g,
        (__attribute__((address_space(3))) unsigned int*)l, 16, 0, 0);
}

#define BM 256
#define BN 256
#define BK 64
#define NTHREADS 512

// LDS map (bytes), 128 KiB: buf d: d*65536; A half h: +h*16384; B half h: +32768+h*16384
// Swizzle (involution, 16B slots): stored = row*128 + (cb ^ ((row&7)<<4))

__device__ inline void stage_half(const unsigned short* g, int row0, int kel, int K,
                                  unsigned ldsbase, char* smem, int tid) {
    const int rl  = tid >> 3;
    const int scb = ((tid & 7) ^ (rl & 7)) << 4;
    char* wb = smem + ldsbase + (unsigned)((tid >> 6) << 10);
#pragma unroll
    for (int s = 0; s < 2; ++s) {
        long off = ((long)(row0 + s * 64 + rl) * K + kel) * 2 + scb;
        async16((const char*)g + off, wb + s * 8192);
    }
}

__device__ inline h16x8 ld_frag(const char* smem, unsigned base, int row, int kbyte) {
    unsigned off = base + (unsigned)(row * 128) + (unsigned)(kbyte ^ ((row & 7) << 4));
    return *(const h16x8*)(smem + off);
}

// bijective XCD-aware workgroup swizzle (m204 form)
__device__ inline void xcd_swizzle(int& bx, int& by, int& bz) {
    const long gx = gridDim.x, gy = gridDim.y;
    const long nwg = gx * gy * (long)gridDim.z;
    const long hw  = ((long)blockIdx.z * gy + blockIdx.y) * gx + blockIdx.x;
    const long qq = nwg >> 3, rr = nwg & 7;
    const long xcd = hw & 7, pos = hw >> 3;
    const long lg = (xcd < rr) ? xcd * (qq + 1) + pos
                               : rr * (qq + 1) + (xcd - rr) * qq + pos;
    bx = (int)(lg % gx);
    const long rem = lg / gx;
    by = (int)(rem % gy);
    bz = (int)(rem / gy);
}

// C = scale*(A . B^T) + bias. A,B f16 row-major pitch K. OM: 0 = f32 out, 1 = f16 out.
// r4 8-phase schedule (T2 swizzle + counted vmcnt + setprio) — best measured config.
template<int OM>
__global__ __launch_bounds__(NTHREADS, 2)
void gemm256(const unsigned short* __restrict__ A,
             const unsigned short* __restrict__ B,
             const float* __restrict__ bias,
             void* __restrict__ C, int N, int K,
             long sA, long sB, long sC, float scale)
{
    __shared__ __align__(16) char smem[131072];

    const int tid  = threadIdx.x;
    const int wv   = tid >> 6;
    const int lane = tid & 63;
    const int wr = wv >> 2, wc = wv & 3;
    const int lrow = lane & 15;
    const int kq16 = (lane >> 4) * 16;

    int bx, by, bz; xcd_swizzle(bx, by, bz);
    const int n0 = bx * BN;
    const int m0 = by * BM;

    const unsigned short* Ag = A + (long)bz * sA;
    const unsigned short* Bg = B + (long)bz * sB;
    const int NT = K / BK;

    auto stageA = [&](int t, int h) {
        stage_half(Ag, m0 + h * 128, t * BK, K,
                   (unsigned)(((t & 1) << 16) + (h << 14)), smem, tid);
    };
    auto stageB = [&](int t, int h) {
        stage_half(Bg, n0 + h * 128, t * BK, K,
                   (unsigned)(((t & 1) << 16) + 32768 + (h << 14)), smem, tid);
    };

    f32x4 acc[8][4];
#pragma unroll
    for (int i = 0; i < 8; ++i)
#pragma unroll
        for (int j = 0; j < 4; ++j) acc[i][j] = (f32x4){0.f, 0.f, 0.f, 0.f};

    const unsigned AbaseW = (unsigned)(wr * 16384);
    const unsigned BbaseW = (unsigned)(32768 + (wc >> 1) * 16384);
    const int brow0 = (wc & 1) * 64;

    stageB(0, 0); stageB(0, 1); stageA(0, 0); stageA(0, 1); stageB(1, 0); stageB(1, 1);
    asm volatile("s_waitcnt vmcnt(4)" ::: "memory");
    __builtin_amdgcn_s_barrier();

    h16x8 bfr[4][2], afr[2][2];

    for (int i = 0; i < NT / 2; ++i) {
        const int t1 = 2 * i + 1, t2 = 2 * i + 2, t3 = 2 * i + 3;
#pragma unroll
        for (int half = 0; half < 2; ++half) {
            const unsigned hb = half ? 65536u : 0u;
#pragma unroll
            for (int q = 0; q < 4; ++q) {
                if (q == 0) {
#pragma unroll
                    for (int j = 0; j < 4; ++j)
#pragma unroll
                        for (int ks = 0; ks < 2; ++ks)
                            bfr[j][ks] = ld_frag(smem, hb + BbaseW, brow0 + j * 16 + lrow, ks * 64 + kq16);
                }
#pragma unroll
                for (int f = 0; f < 2; ++f)
#pragma unroll
                    for (int ks = 0; ks < 2; ++ks)
                        afr[f][ks] = ld_frag(smem, hb + AbaseW, q * 32 + f * 16 + lrow, ks * 64 + kq16);
                if (half == 0) {
                    if (q == 0)      stageA(t1, 0);
                    else if (q == 1) stageA(t1, 1);
                    else if (q == 2) { if (t2 < NT) stageB(t2, 0); }
                    else             { if (t2 < NT) stageB(t2, 1); }
                } else {
                    if (q == 0)      { if (t2 < NT) stageA(t2, 0); }
                    else if (q == 1) { if (t2 < NT) stageA(t2, 1); }
                    else if (q == 2) { if (t3 < NT) stageB(t3, 0); }
                    else             { if (t3 < NT) stageB(t3, 1); }
                }

                __builtin_amdgcn_s_barrier();
                asm volatile("s_waitcnt lgkmcnt(0)" ::: "memory");
                __builtin_amdgcn_sched_barrier(0);
                __builtin_amdgcn_s_setprio(1);
#pragma unroll
                for (int ks = 0; ks < 2; ++ks)
#pragma unroll
                    for (int f = 0; f < 2; ++f)
#pragma unroll
                        for (int j = 0; j < 4; ++j)
                            acc[2 * q + f][j] = __builtin_amdgcn_mfma_f32_16x16x32_f16(
                                afr[f][ks], bfr[j][ks], acc[2 * q + f][j], 0, 0, 0);
                __builtin_amdgcn_s_setprio(0);
                if (q == 3) {
                    const int tn = half ? t3 : t2;
                    if (tn < NT) { asm volatile("s_waitcnt vmcnt(4)" ::: "memory"); }
                    else         { asm volatile("s_waitcnt vmcnt(0)" ::: "memory"); }
                }
                __builtin_amdgcn_s_barrier();
            }
        }
    }

#pragma unroll
    for (int j = 0; j < 4; ++j) {
        const int col = n0 + wc * 64 + j * 16 + lrow;
        const float bb = bias ? bias[col] : 0.f;
#pragma unroll
        for (int mi = 0; mi < 8; ++mi) {
#pragma unroll
            for (int r = 0; r < 4; ++r) {
                const long row = m0 + wr * 128 + mi * 16 + (lane >> 4) * 4 + r;
                const float v = acc[mi][j][r] * scale + bb;
                const long idx = (long)bz * sC + row * (long)N + col;
                if constexpr (OM == 0) ((float*)C)[idx] = v;
                else                   ((unsigned short*)C)[idx] = f2h(v);
            }
        }
    }
}

// fp32 -> fp16 conversion, 4 elems/thread
__global__ __launch_bounds__(256)
void conv_f16(const float* __restrict__ in, unsigned short* __restrict__ out, int n)
{
    int i = (blockIdx.x * 256 + threadIdx.x) * 4;
    if (i >= n) return;
    float4 v = *(const float4*)(in + i);
    s16x4 o = {(short)f2h(v.x), (short)f2h(v.y), (short)f2h(v.z), (short)f2h(v.w)};
    *(s16x4*)(out + i) = o;
}

// values [16][1024][1024] f32 -> vT f16 (per-batch transpose)
__global__ __launch_bounds__(256)
void transpose_f16(const float* __restrict__ in, unsigned short* __restrict__ out)
{
    __shared__ float tile[32][33];
    const long base = (long)blockIdx.z * 1024 * 1024;
    const int h0 = blockIdx.x * 32, t0 = blockIdx.y * 32;
    for (int i = threadIdx.y; i < 32; i += 8)
        tile[i][threadIdx.x] = in[base + (long)(t0 + i) * 1024 + h0 + threadIdx.x];
    __syncthreads();
    for (int i = threadIdx.y; i < 32; i += 8)
        out[base + (long)(h0 + i) * 1024 + t0 + threadIdx.x] = f2h(tile[threadIdx.x][i]);
}

// in-place row softmax on fp16 logits (1024/row)
__global__ __launch_bounds__(256)
void softmax_ip(unsigned short* __restrict__ S)
{
    long row = blockIdx.x;
    const int tid = threadIdx.x;
    s16x4 raw = *(s16x4*)(S + row * 1024 + tid * 4);
    float v0 = h2f((unsigned short)raw[0]), v1 = h2f((unsigned short)raw[1]);
    float v2 = h2f((unsigned short)raw[2]), v3 = h2f((unsigned short)raw[3]);
    float m = fmaxf(fmaxf(v0, v1), fmaxf(v2, v3));
#pragma unroll
    for (int off = 1; off < 64; off <<= 1) m = fmaxf(m, __shfl_xor(m, off));
    __shared__ float redm[4];
    int wave = tid >> 6, lane = tid & 63;
    if (lane == 0) redm[wave] = m;
    __syncthreads();
    m = fmaxf(fmaxf(redm[0], redm[1]), fmaxf(redm[2], redm[3]));

    float e0 = expf(v0 - m), e1 = expf(v1 - m), e2 = expf(v2 - m), e3 = expf(v3 - m);
    float s = e0 + e1 + e2 + e3;
#pragma unroll
    for (int off = 1; off < 64; off <<= 1) s += __shfl_xor(s, off);
    __shared__ float reds[4];
    if (lane == 0) reds[wave] = s;
    __syncthreads();
    s = reds[0] + reds[1] + reds[2] + reds[3];
    float inv = 1.f / s;
    s16x4 o = {(short)f2h(e0 * inv), (short)f2h(e1 * inv),
               (short)f2h(e2 * inv), (short)f2h(e3 * inv)};
    *(s16x4*)(S + row * 1024 + tid * 4) = o;
}

extern "C" void kernel_launch(void* const* d_in, const int* in_sizes, int n_in,
                              void* d_out, int out_size, void* d_ws, size_t ws_size,
                              hipStream_t stream)
{
    const float* query  = (const float*)d_in[0];
    const float* keys   = (const float*)d_in[1];
    const float* values = (const float*)d_in[2];
    const float* Wq     = (const float*)d_in[3];
    const float* bq     = (const float*)d_in[4];
    const float* Wk     = (const float*)d_in[5];
    const float* bk     = (const float*)d_in[6];
    const float* Wo     = (const float*)d_in[7];
    const float* bo     = (const float*)d_in[8];

    const int  T = 1024, H = 1024;
    const long NE = 16384L * 1024;   // B*T*H (== B*T*T in elements)
    const long NW = 1024L * 1024;

    size_t need = (size_t)(NE * 5 + NW * 3) * sizeof(unsigned short);
    if (ws_size < need) return;

    unsigned short* ws  = (unsigned short*)d_ws;
    unsigned short* Xq  = ws;             // query f16 (dead after stage 1)
    unsigned short* Xk  = Xq + NE;        // keys f16  (dead after stage 2)
    unsigned short* qf  = Xk + NE;
    unsigned short* kf  = qf + NE;
    unsigned short* vT  = kf + NE;
    unsigned short* Wqh = vT + NE;
    unsigned short* Wkh = Wqh + NW;
    unsigned short* Woh = Wkh + NW;
    unsigned short* sc  = Xq;             // alias: f16 scores -> probs (in place)
    unsigned short* ctx = Xk;             // alias: context

    // ---- prep: f32 -> f16 ----
    conv_f16<<<16384, 256, 0, stream>>>(query, Xq, (int)NE);
    conv_f16<<<16384, 256, 0, stream>>>(keys,  Xk, (int)NE);
    conv_f16<<<1024,  256, 0, stream>>>(Wq, Wqh, (int)NW);
    conv_f16<<<1024,  256, 0, stream>>>(Wk, Wkh, (int)NW);
    conv_f16<<<1024,  256, 0, stream>>>(Wo, Woh, (int)NW);
    transpose_f16<<<dim3(32, 32, 16), dim3(32, 8), 0, stream>>>(values, vT);

    // 1. q = query @ Wq^T + bq   (f16 out)   grid 4x64 = 256 WG
    gemm256<1><<<dim3(4, 64, 1), NTHREADS, 0, stream>>>(
        Xq, Wqh, bq, qf, H, H, 0, 0, 0, 1.f);
    // 2. k = keys @ Wk^T + bk
    gemm256<1><<<dim3(4, 64, 1), NTHREADS, 0, stream>>>(
        Xk, Wkh, bk, kf, H, H, 0, 0, 0, 1.f);
    // 3. scores = q @ k^T (batched, f16 out; overwrites Xq which is now dead)
    gemm256<1><<<dim3(4, 4, 16), NTHREADS, 0, stream>>>(
        qf, kf, nullptr, sc, T, H, (long)T * H, (long)T * H, (long)T * T, 1.f);
    // 4. softmax in place (f16 -> f16)
    softmax_ip<<<16384, 256, 0, stream>>>(sc);
    // 5. ctx = attn @ vT^T / 32 (batched, f16 out; overwrites Xk)
    gemm256<1><<<dim3(4, 4, 16), NTHREADS, 0, stream>>>(
        sc, vT, nullptr, ctx, H, T, (long)T * T, (long)T * H, (long)T * H, 1.f / 32.f);
    // 6. out = ctx @ Wo^T + bo (f32 out)
    gemm256<0><<<dim3(4, 64, 1), NTHREADS, 0, stream>>>(
        ctx, Woh, bo, d_out, H, H, 0, 0, 0, 1.f);
}

// Round 8
// 306.594 us; speedup vs baseline: 1.0473x; 1.0199x over previous
//
#include <hip/hip_runtime.h>
#include <math.h>

typedef __attribute__((ext_vector_type(4))) float f32x4;
typedef __attribute__((ext_vector_type(8))) _Float16 h16x8;
typedef __attribute__((ext_vector_type(8))) short s16x8;
typedef __attribute__((ext_vector_type(4))) short s16x4;

__device__ inline unsigned short f2h(float f) {
    union { _Float16 h; unsigned short u; } v; v.h = (_Float16)f; return v.u;
}
__device__ inline float h2f(unsigned short u) {
    union { unsigned short u; _Float16 h; } v; v.u = u; return (float)v.h;
}

__device__ inline void async16(const void* g, void* l) {
    __builtin_amdgcn_global_load_lds(
        (const __attribute__((address_space(1))) unsigned int*)g,
        (__attribute__((address_space(3))) unsigned int*)l, 16, 0, 0);
}

#define BM 256
#define BN 256
#define BK 64
#define NTHREADS 512

// LDS map (bytes), 128 KiB: buf d: d*65536; A half h: +h*16384; B half h: +32768+h*16384
// Swizzle (involution, 16B slots): stored = row*128 + (cb ^ ((row&7)<<4))

__device__ inline void stage_half(const unsigned short* g, int row0, int kel, int pitch,
                                  unsigned ldsbase, char* smem, int tid) {
    const int rl  = tid >> 3;
    const int scb = ((tid & 7) ^ (rl & 7)) << 4;
    char* wb = smem + ldsbase + (unsigned)((tid >> 6) << 10);
#pragma unroll
    for (int s = 0; s < 2; ++s) {
        long off = ((long)(row0 + s * 64 + rl) * pitch + kel) * 2 + scb;
        async16((const char*)g + off, wb + s * 8192);
    }
}

__device__ inline h16x8 ld_frag(const char* smem, unsigned base, int row, int kbyte) {
    unsigned off = base + (unsigned)(row * 128) + (unsigned)(kbyte ^ ((row & 7) << 4));
    return *(const h16x8*)(smem + off);
}

// bijective XCD-aware workgroup swizzle (m204 form)
__device__ inline void xcd_swizzle(int& bx, int& by, int& bz) {
    const long gx = gridDim.x, gy = gridDim.y;
    const long nwg = gx * gy * (long)gridDim.z;
    const long hw  = ((long)blockIdx.z * gy + blockIdx.y) * gx + blockIdx.x;
    const long qq = nwg >> 3, rr = nwg & 7;
    const long xcd = hw & 7, pos = hw >> 3;
    const long lg = (xcd < rr) ? xcd * (qq + 1) + pos
                               : rr * (qq + 1) + (xcd - rr) * qq + pos;
    bx = (int)(lg % gx);
    const long rem = lg / gx;
    by = (int)(rem % gy);
    bz = (int)(rem / gy);
}

// C = scale*(A . B^T) + bias[bz*sBias + col]. A,B f16 rows of `pitch` elements;
// K-loop length lenK (<= pitch; chunk offset via sA/sB). OM: 0 = f32 out, 1 = f16 out.
// r4 8-phase schedule (T2 swizzle + counted vmcnt + setprio).
template<int OM>
__global__ __launch_bounds__(NTHREADS, 2)
void gemm256(const unsigned short* __restrict__ A,
             const unsigned short* __restrict__ B,
             const float* __restrict__ bias,
             void* __restrict__ C, int N, int lenK, int pitch,
             long sA, long sB, long sC, long sBias, float scale)
{
    __shared__ __align__(16) char smem[131072];

    const int tid  = threadIdx.x;
    const int wv   = tid >> 6;
    const int lane = tid & 63;
    const int wr = wv >> 2, wc = wv & 3;
    const int lrow = lane & 15;
    const int kq16 = (lane >> 4) * 16;

    int bx, by, bz; xcd_swizzle(bx, by, bz);
    const int n0 = bx * BN;
    const int m0 = by * BM;

    const unsigned short* Ag = A + (long)bz * sA;
    const unsigned short* Bg = B + (long)bz * sB;
    const int NT = lenK / BK;

    auto stageA = [&](int t, int h) {
        stage_half(Ag, m0 + h * 128, t * BK, pitch,
                   (unsigned)(((t & 1) << 16) + (h << 14)), smem, tid);
    };
    auto stageB = [&](int t, int h) {
        stage_half(Bg, n0 + h * 128, t * BK, pitch,
                   (unsigned)(((t & 1) << 16) + 32768 + (h << 14)), smem, tid);
    };

    f32x4 acc[8][4];
#pragma unroll
    for (int i = 0; i < 8; ++i)
#pragma unroll
        for (int j = 0; j < 4; ++j) acc[i][j] = (f32x4){0.f, 0.f, 0.f, 0.f};

    const unsigned AbaseW = (unsigned)(wr * 16384);
    const unsigned BbaseW = (unsigned)(32768 + (wc >> 1) * 16384);
    const int brow0 = (wc & 1) * 64;

    stageB(0, 0); stageB(0, 1); stageA(0, 0); stageA(0, 1); stageB(1, 0); stageB(1, 1);
    asm volatile("s_waitcnt vmcnt(4)" ::: "memory");
    __builtin_amdgcn_s_barrier();

    h16x8 bfr[4][2], afr[2][2];

    for (int i = 0; i < NT / 2; ++i) {
        const int t1 = 2 * i + 1, t2 = 2 * i + 2, t3 = 2 * i + 3;
#pragma unroll
        for (int half = 0; half < 2; ++half) {
            const unsigned hb = half ? 65536u : 0u;
#pragma unroll
            for (int q = 0; q < 4; ++q) {
                if (q == 0) {
#pragma unroll
                    for (int j = 0; j < 4; ++j)
#pragma unroll
                        for (int ks = 0; ks < 2; ++ks)
                            bfr[j][ks] = ld_frag(smem, hb + BbaseW, brow0 + j * 16 + lrow, ks * 64 + kq16);
                }
#pragma unroll
                for (int f = 0; f < 2; ++f)
#pragma unroll
                    for (int ks = 0; ks < 2; ++ks)
                        afr[f][ks] = ld_frag(smem, hb + AbaseW, q * 32 + f * 16 + lrow, ks * 64 + kq16);
                if (half == 0) {
                    if (q == 0)      stageA(t1, 0);
                    else if (q == 1) stageA(t1, 1);
                    else if (q == 2) { if (t2 < NT) stageB(t2, 0); }
                    else             { if (t2 < NT) stageB(t2, 1); }
                } else {
                    if (q == 0)      { if (t2 < NT) stageA(t2, 0); }
                    else if (q == 1) { if (t2 < NT) stageA(t2, 1); }
                    else if (q == 2) { if (t3 < NT) stageB(t3, 0); }
                    else             { if (t3 < NT) stageB(t3, 1); }
                }

                __builtin_amdgcn_s_barrier();
                asm volatile("s_waitcnt lgkmcnt(0)" ::: "memory");
                __builtin_amdgcn_sched_barrier(0);
                __builtin_amdgcn_s_setprio(1);
#pragma unroll
                for (int ks = 0; ks < 2; ++ks)
#pragma unroll
                    for (int f = 0; f < 2; ++f)
#pragma unroll
                        for (int j = 0; j < 4; ++j)
                            acc[2 * q + f][j] = __builtin_amdgcn_mfma_f32_16x16x32_f16(
                                afr[f][ks], bfr[j][ks], acc[2 * q + f][j], 0, 0, 0);
                __builtin_amdgcn_s_setprio(0);
                if (q == 3) {
                    const int tn = half ? t3 : t2;
                    if (tn < NT) { asm volatile("s_waitcnt vmcnt(4)" ::: "memory"); }
                    else         { asm volatile("s_waitcnt vmcnt(0)" ::: "memory"); }
                }
                __builtin_amdgcn_s_barrier();
            }
        }
    }

#pragma unroll
    for (int j = 0; j < 4; ++j) {
        const int col = n0 + wc * 64 + j * 16 + lrow;
        const float bb = bias ? bias[(long)bz * sBias + col] : 0.f;
#pragma unroll
        for (int mi = 0; mi < 8; ++mi) {
#pragma unroll
            for (int r = 0; r < 4; ++r) {
                const long row = m0 + wr * 128 + mi * 16 + (lane >> 4) * 4 + r;
                const float v = acc[mi][j][r] * scale + bb;
                const long idx = (long)bz * sC + row * (long)N + col;
                if constexpr (OM == 0) ((float*)C)[idx] = v;
                else                   ((unsigned short*)C)[idx] = f2h(v);
            }
        }
    }
}

// fp32 -> fp16 conversion, 4 elems/thread
__global__ __launch_bounds__(256)
void conv_f16(const float* __restrict__ in, unsigned short* __restrict__ out, int n)
{
    int i = (blockIdx.x * 256 + threadIdx.x) * 4;
    if (i >= n) return;
    float4 v = *(const float4*)(in + i);
    s16x4 o = {(short)f2h(v.x), (short)f2h(v.y), (short)f2h(v.z), (short)f2h(v.w)};
    *(s16x4*)(out + i) = o;
}

// [z][1024][1024] f32 -> f16 transpose per z-slice
__global__ __launch_bounds__(256)
void transpose_f16(const float* __restrict__ in, unsigned short* __restrict__ out)
{
    __shared__ float tile[32][33];
    const long base = (long)blockIdx.z * 1024 * 1024;
    const int h0 = blockIdx.x * 32, t0 = blockIdx.y * 32;
    for (int i = threadIdx.y; i < 32; i += 8)
        tile[i][threadIdx.x] = in[base + (long)(t0 + i) * 1024 + h0 + threadIdx.x];
    __syncthreads();
    for (int i = threadIdx.y; i < 32; i += 8)
        out[base + (long)(h0 + i) * 1024 + t0 + threadIdx.x] = f2h(tile[threadIdx.x][i]);
}

// w2[h] = sum_o Wk[o][h] * bq[o]   (Wk f32 [1024][1024], bq f32[1024])
__global__ __launch_bounds__(256)
void w2_kernel(const float* __restrict__ Wk, const float* __restrict__ bq,
               float* __restrict__ w2)
{
    __shared__ float part[4][64];
    const int tx = threadIdx.x & 63;      // col within chunk
    const int ty = threadIdx.x >> 6;      // row group
    const int h  = blockIdx.x * 64 + tx;
    float s = 0.f;
    for (int o = ty * 256; o < ty * 256 + 256; ++o)
        s = fmaf(Wk[(long)o * 1024 + h], bq[o], s);
    part[ty][tx] = s;
    __syncthreads();
    if (ty == 0) w2[h] = part[0][tx] + part[1][tx] + part[2][tx] + part[3][tx];
}

// v[r] = sum_h Xk[r][h] * w2[h]   (Xk f16 [16384][1024], w2 f32)
__global__ __launch_bounds__(256)
void matvec_v(const unsigned short* __restrict__ Xk, const float* __restrict__ w2,
              float* __restrict__ v)
{
    const int wave = threadIdx.x >> 6, lane = threadIdx.x & 63;
    const long row = (long)blockIdx.x * 4 + wave;
    const unsigned short* p = Xk + row * 1024 + lane * 16;
    float s = 0.f;
#pragma unroll
    for (int c = 0; c < 2; ++c) {
        s16x8 hv = *(const s16x8*)(p + c * 8);
#pragma unroll
        for (int e = 0; e < 8; ++e)
            s = fmaf(h2f((unsigned short)hv[e]), w2[lane * 16 + c * 8 + e], s);
    }
#pragma unroll
    for (int off = 1; off < 64; off <<= 1) s += __shfl_xor(s, off);
    if (lane == 0) v[row] = s;
}

// MT f16 = sum of 4 f32 partial slabs
__global__ __launch_bounds__(256)
void reduce4(const float* __restrict__ p, unsigned short* __restrict__ MT)
{
    const long i = ((long)blockIdx.x * 256 + threadIdx.x) * 4;
    const long S = 1024L * 1024;
    float4 a = *(const float4*)(p + i);
    float4 b = *(const float4*)(p + S + i);
    float4 c = *(const float4*)(p + 2 * S + i);
    float4 d = *(const float4*)(p + 3 * S + i);
    s16x4 o = {(short)f2h(a.x + b.x + c.x + d.x), (short)f2h(a.y + b.y + c.y + d.y),
               (short)f2h(a.z + b.z + c.z + d.z), (short)f2h(a.w + b.w + c.w + d.w)};
    *(s16x4*)(MT + i) = o;
}

// in-place row softmax on fp16 logits (1024/row)
__global__ __launch_bounds__(256)
void softmax_ip(unsigned short* __restrict__ S)
{
    long row = blockIdx.x;
    const int tid = threadIdx.x;
    s16x4 raw = *(s16x4*)(S + row * 1024 + tid * 4);
    float v0 = h2f((unsigned short)raw[0]), v1 = h2f((unsigned short)raw[1]);
    float v2 = h2f((unsigned short)raw[2]), v3 = h2f((unsigned short)raw[3]);
    float m = fmaxf(fmaxf(v0, v1), fmaxf(v2, v3));
#pragma unroll
    for (int off = 1; off < 64; off <<= 1) m = fmaxf(m, __shfl_xor(m, off));
    __shared__ float redm[4];
    int wave = tid >> 6, lane = tid & 63;
    if (lane == 0) redm[wave] = m;
    __syncthreads();
    m = fmaxf(fmaxf(redm[0], redm[1]), fmaxf(redm[2], redm[3]));

    float e0 = expf(v0 - m), e1 = expf(v1 - m), e2 = expf(v2 - m), e3 = expf(v3 - m);
    float s = e0 + e1 + e2 + e3;
#pragma unroll
    for (int off = 1; off < 64; off <<= 1) s += __shfl_xor(s, off);
    __shared__ float reds[4];
    if (lane == 0) reds[wave] = s;
    __syncthreads();
    s = reds[0] + reds[1] + reds[2] + reds[3];
    float inv = 1.f / s;
    s16x4 o = {(short)f2h(e0 * inv), (short)f2h(e1 * inv),
               (short)f2h(e2 * inv), (short)f2h(e3 * inv)};
    *(s16x4*)(S + row * 1024 + tid * 4) = o;
}

extern "C" void kernel_launch(void* const* d_in, const int* in_sizes, int n_in,
                              void* d_out, int out_size, void* d_ws, size_t ws_size,
                              hipStream_t stream)
{
    const float* query  = (const float*)d_in[0];
    const float* keys   = (const float*)d_in[1];
    const float* values = (const float*)d_in[2];
    const float* Wq     = (const float*)d_in[3];
    const float* bq     = (const float*)d_in[4];
    const float* Wk     = (const float*)d_in[5];
    const float* bk     = (const float*)d_in[6];   // drops out of softmax (row-const terms)
    const float* Wo     = (const float*)d_in[7];
    const float* bo     = (const float*)d_in[8];
    (void)bk;

    const int  T = 1024, H = 1024;
    const long NE = 16384L * 1024;
    const long NW = 1024L * 1024;

    size_t need = (size_t)(NE * 4 + NW * 12 + 40960) * sizeof(unsigned short);
    if (ws_size < need) return;

    unsigned short* ws   = (unsigned short*)d_ws;
    unsigned short* Xq   = ws;                 // query f16 (dead after P1) -> sc
    unsigned short* Xk   = Xq + NE;            // keys f16 (live through scores + v)
    unsigned short* vT   = Xk + NE;            // values^T f16
    unsigned short* P1   = vT + NE;            // Q*M^T f16 (dead after scores) -> ctx
    unsigned short* WqT  = P1 + NE;            // Wq^T f16
    unsigned short* WkT  = WqT + NW;           // Wk^T f16
    unsigned short* Woh  = WkT + NW;           // Wo f16
    unsigned short* MT   = Woh + NW;           // M^T = Wk^T*Wq  f16
    float*          part = (float*)(MT + NW);  // 4 f32 partial slabs (8*NW ushorts)
    float*          w2   = (float*)(MT + NW * 9);   // 1024 f32
    float*          vvec = w2 + 1024;               // 16384 f32
    unsigned short* sc   = Xq;
    unsigned short* ctx  = P1;

    // ---- prep ----
    conv_f16<<<16384, 256, 0, stream>>>(query, Xq, (int)NE);
    conv_f16<<<16384, 256, 0, stream>>>(keys,  Xk, (int)NE);
    transpose_f16<<<dim3(32, 32, 1), dim3(32, 8), 0, stream>>>(Wq, WqT);
    transpose_f16<<<dim3(32, 32, 1), dim3(32, 8), 0, stream>>>(Wk, WkT);
    conv_f16<<<1024, 256, 0, stream>>>(Wo, Woh, (int)NW);
    transpose_f16<<<dim3(32, 32, 16), dim3(32, 8), 0, stream>>>(values, vT);
    w2_kernel<<<16, 256, 0, stream>>>(Wk, bq, w2);

    // ---- MT = Wk^T * Wq  (split-K=4, f32 partials, then reduce) ----
    gemm256<0><<<dim3(4, 4, 4), NTHREADS, 0, stream>>>(
        WkT, WqT, nullptr, part, 1024, 256, 1024, 256, 256, (long)NW, 0, 1.f);
    reduce4<<<1024, 256, 0, stream>>>(part, MT);

    // ---- P1 = Xq . MT^T  (34 GF, full grid) ----
    gemm256<1><<<dim3(4, 64, 1), NTHREADS, 0, stream>>>(
        Xq, MT, nullptr, P1, H, H, H, 0, 0, 0, 0, 1.f);

    // ---- v = Xk . w2 (per-batch column bias of scores) ----
    matvec_v<<<4096, 256, 0, stream>>>(Xk, w2, vvec);

    // ---- scores = P1 . Xk^T + v[s]  (batched, f16 out) ----
    gemm256<1><<<dim3(4, 4, 16), NTHREADS, 0, stream>>>(
        P1, Xk, vvec, sc, T, H, H,
        (long)T * H, (long)T * H, (long)T * T, (long)T, 1.f);

    // ---- softmax in place ----
    softmax_ip<<<16384, 256, 0, stream>>>(sc);

    // ---- ctx = attn . vT^T / 32 ----
    gemm256<1><<<dim3(4, 4, 16), NTHREADS, 0, stream>>>(
        sc, vT, nullptr, ctx, H, T, T,
        (long)T * T, (long)T * H, (long)T * H, 0, 1.f / 32.f);

    // ---- out = ctx . Wo^T + bo ----
    gemm256<0><<<dim3(4, 64, 1), NTHREADS, 0, stream>>>(
        ctx, Woh, bo, d_out, H, H, H, 0, 0, 0, 0, 1.f);
}

// Round 9
// 300.140 us; speedup vs baseline: 1.0698x; 1.0215x over previous
//
#include <hip/hip_runtime.h>
#include <math.h>

typedef __attribute__((ext_vector_type(4))) float f32x4;
typedef __attribute__((ext_vector_type(8))) _Float16 h16x8;
typedef __attribute__((ext_vector_type(8))) short s16x8;
typedef __attribute__((ext_vector_type(4))) short s16x4;

__device__ inline unsigned short f2h(float f) {
    union { _Float16 h; unsigned short u; } v; v.h = (_Float16)f; return v.u;
}
__device__ inline float h2f(unsigned short u) {
    union { unsigned short u; _Float16 h; } v; v.u = u; return (float)v.h;
}

__device__ inline void async16(const void* g, void* l) {
    __builtin_amdgcn_global_load_lds(
        (const __attribute__((address_space(1))) unsigned int*)g,
        (__attribute__((address_space(3))) unsigned int*)l, 16, 0, 0);
}

// bijective XCD-aware workgroup swizzle (m204 form)
__device__ inline void xcd_swizzle(int& bx, int& by, int& bz) {
    const long gx = gridDim.x, gy = gridDim.y;
    const long nwg = gx * gy * (long)gridDim.z;
    const long hw  = ((long)blockIdx.z * gy + blockIdx.y) * gx + blockIdx.x;
    const long qq = nwg >> 3, rr = nwg & 7;
    const long xcd = hw & 7, pos = hw >> 3;
    const long lg = (xcd < rr) ? xcd * (qq + 1) + pos
                               : rr * (qq + 1) + (xcd - rr) * qq + pos;
    bx = (int)(lg % gx);
    const long rem = lg / gx;
    by = (int)(rem % gy);
    bz = (int)(rem / gy);
}

// ======================= gemm256: 256x256, BK=64, 8-phase =======================
#define BM 256
#define BN 256
#define BK 64
#define NTHREADS 512

__device__ inline void stage_half(const unsigned short* g, int row0, int kel, int pitch,
                                  unsigned ldsbase, char* smem, int tid) {
    const int rl  = tid >> 3;
    const int scb = ((tid & 7) ^ (rl & 7)) << 4;
    char* wb = smem + ldsbase + (unsigned)((tid >> 6) << 10);
#pragma unroll
    for (int s = 0; s < 2; ++s) {
        long off = ((long)(row0 + s * 64 + rl) * pitch + kel) * 2 + scb;
        async16((const char*)g + off, wb + s * 8192);
    }
}

__device__ inline h16x8 ld_frag(const char* smem, unsigned base, int row, int kbyte) {
    unsigned off = base + (unsigned)(row * 128) + (unsigned)(kbyte ^ ((row & 7) << 4));
    return *(const h16x8*)(smem + off);
}

template<int OM>
__global__ __launch_bounds__(NTHREADS, 2)
void gemm256(const unsigned short* __restrict__ A,
             const unsigned short* __restrict__ B,
             const float* __restrict__ bias,
             void* __restrict__ C, int N, int lenK, int pitch,
             long sA, long sB, long sC, long sBias, float scale)
{
    __shared__ __align__(16) char smem[131072];

    const int tid  = threadIdx.x;
    const int wv   = tid >> 6;
    const int lane = tid & 63;
    const int wr = wv >> 2, wc = wv & 3;
    const int lrow = lane & 15;
    const int kq16 = (lane >> 4) * 16;

    int bx, by, bz; xcd_swizzle(bx, by, bz);
    const int n0 = bx * BN;
    const int m0 = by * BM;

    const unsigned short* Ag = A + (long)bz * sA;
    const unsigned short* Bg = B + (long)bz * sB;
    const int NT = lenK / BK;

    auto stageA = [&](int t, int h) {
        stage_half(Ag, m0 + h * 128, t * BK, pitch,
                   (unsigned)(((t & 1) << 16) + (h << 14)), smem, tid);
    };
    auto stageB = [&](int t, int h) {
        stage_half(Bg, n0 + h * 128, t * BK, pitch,
                   (unsigned)(((t & 1) << 16) + 32768 + (h << 14)), smem, tid);
    };

    f32x4 acc[8][4];
#pragma unroll
    for (int i = 0; i < 8; ++i)
#pragma unroll
        for (int j = 0; j < 4; ++j) acc[i][j] = (f32x4){0.f, 0.f, 0.f, 0.f};

    const unsigned AbaseW = (unsigned)(wr * 16384);
    const unsigned BbaseW = (unsigned)(32768 + (wc >> 1) * 16384);
    const int brow0 = (wc & 1) * 64;

    stageB(0, 0); stageB(0, 1); stageA(0, 0); stageA(0, 1); stageB(1, 0); stageB(1, 1);
    asm volatile("s_waitcnt vmcnt(4)" ::: "memory");
    __builtin_amdgcn_s_barrier();

    h16x8 bfr[4][2], afr[2][2];

    for (int i = 0; i < NT / 2; ++i) {
        const int t1 = 2 * i + 1, t2 = 2 * i + 2, t3 = 2 * i + 3;
#pragma unroll
        for (int half = 0; half < 2; ++half) {
            const unsigned hb = half ? 65536u : 0u;
#pragma unroll
            for (int q = 0; q < 4; ++q) {
                if (q == 0) {
#pragma unroll
                    for (int j = 0; j < 4; ++j)
#pragma unroll
                        for (int ks = 0; ks < 2; ++ks)
                            bfr[j][ks] = ld_frag(smem, hb + BbaseW, brow0 + j * 16 + lrow, ks * 64 + kq16);
                }
#pragma unroll
                for (int f = 0; f < 2; ++f)
#pragma unroll
                    for (int ks = 0; ks < 2; ++ks)
                        afr[f][ks] = ld_frag(smem, hb + AbaseW, q * 32 + f * 16 + lrow, ks * 64 + kq16);
                if (half == 0) {
                    if (q == 0)      stageA(t1, 0);
                    else if (q == 1) stageA(t1, 1);
                    else if (q == 2) { if (t2 < NT) stageB(t2, 0); }
                    else             { if (t2 < NT) stageB(t2, 1); }
                } else {
                    if (q == 0)      { if (t2 < NT) stageA(t2, 0); }
                    else if (q == 1) { if (t2 < NT) stageA(t2, 1); }
                    else if (q == 2) { if (t3 < NT) stageB(t3, 0); }
                    else             { if (t3 < NT) stageB(t3, 1); }
                }

                __builtin_amdgcn_s_barrier();
                asm volatile("s_waitcnt lgkmcnt(0)" ::: "memory");
                __builtin_amdgcn_sched_barrier(0);
                __builtin_amdgcn_s_setprio(1);
#pragma unroll
                for (int ks = 0; ks < 2; ++ks)
#pragma unroll
                    for (int f = 0; f < 2; ++f)
#pragma unroll
                        for (int j = 0; j < 4; ++j)
                            acc[2 * q + f][j] = __builtin_amdgcn_mfma_f32_16x16x32_f16(
                                afr[f][ks], bfr[j][ks], acc[2 * q + f][j], 0, 0, 0);
                __builtin_amdgcn_s_setprio(0);
                if (q == 3) {
                    const int tn = half ? t3 : t2;
                    if (tn < NT) { asm volatile("s_waitcnt vmcnt(4)" ::: "memory"); }
                    else         { asm volatile("s_waitcnt vmcnt(0)" ::: "memory"); }
                }
                __builtin_amdgcn_s_barrier();
            }
        }
    }

#pragma unroll
    for (int j = 0; j < 4; ++j) {
        const int col = n0 + wc * 64 + j * 16 + lrow;
        const float bb = bias ? bias[(long)bz * sBias + col] : 0.f;
#pragma unroll
        for (int mi = 0; mi < 8; ++mi) {
#pragma unroll
            for (int r = 0; r < 4; ++r) {
                const long row = m0 + wr * 128 + mi * 16 + (lane >> 4) * 4 + r;
                const float v = acc[mi][j][r] * scale + bb;
                const long idx = (long)bz * sC + row * (long)N + col;
                if constexpr (OM == 0) ((float*)C)[idx] = v;
                else                   ((unsigned short*)C)[idx] = f2h(v);
            }
        }
    }
}

// ===== gemm128: 128x256, BK=32, 48 KiB LDS dbuf -> 2 blocks/CU (TLP bet) =====
#define BM2 128
#define BN2 256
#define BK2 32
// LDS: buf d at d*24576; A (8 KB) at +0; B (16 KB) at +8192.
// 64-B rows, 4 16B slots; swizzle slot ^= row&3 (involution).

__device__ inline h16x8 ld_frag32(const char* smem, unsigned base, int row, int kbyte) {
    unsigned off = base + (unsigned)(row * 64) + (unsigned)(kbyte ^ ((row & 3) << 4));
    return *(const h16x8*)(smem + off);
}

template<int OM>
__global__ __launch_bounds__(512, 4)
void gemm128(const unsigned short* __restrict__ A,
             const unsigned short* __restrict__ B,
             const float* __restrict__ bias,
             void* __restrict__ C, int N, int lenK, int pitch,
             long sA, long sB, long sC, long sBias, float scale)
{
    __shared__ __align__(16) char smem[49152];

    const int tid  = threadIdx.x;
    const int wv   = tid >> 6;
    const int lane = tid & 63;
    const int wr = wv >> 2, wc = wv & 3;       // 2M x 4N waves, 64x64 each
    const int lrow = lane & 15;
    const int kq16 = (lane >> 4) * 16;

    int bx, by, bz; xcd_swizzle(bx, by, bz);
    const int n0 = bx * BN2;
    const int m0 = by * BM2;

    const unsigned short* Ag = A + (long)bz * sA;
    const unsigned short* Bg = B + (long)bz * sB;
    const int NT = lenK / BK2;

    auto stage = [&](int t) {
        const unsigned db = (unsigned)((t & 1) * 24576);
        {
            int r = tid >> 2, s = tid & 3, ss = s ^ (r & 3);
            async16((const char*)Ag + ((long)(m0 + r) * pitch + t * BK2 + ss * 8) * 2,
                    smem + db + (unsigned)(wv << 10));
        }
#pragma unroll
        for (int l = 0; l < 2; ++l) {
            int idx = l * 512 + tid;
            int r = idx >> 2, s = idx & 3, ss = s ^ (r & 3);
            async16((const char*)Bg + ((long)(n0 + r) * pitch + t * BK2 + ss * 8) * 2,
                    smem + db + 8192u + (unsigned)(l * 8192) + (unsigned)(wv << 10));
        }
    };

    f32x4 acc[4][4];
#pragma unroll
    for (int i = 0; i < 4; ++i)
#pragma unroll
        for (int j = 0; j < 4; ++j) acc[i][j] = (f32x4){0.f, 0.f, 0.f, 0.f};

    const unsigned Abase = (unsigned)(wr * 4096);
    const unsigned Bbase = 8192u + (unsigned)(wc * 4096);

    stage(0);
    __syncthreads();

#pragma unroll 2
    for (int t = 0; t < NT; ++t) {
        const unsigned db = (unsigned)((t & 1) * 24576);
        if (t + 1 < NT) stage(t + 1);       // other buffer; safe across 1 barrier
        h16x8 afr[4], bfr[4];
#pragma unroll
        for (int f = 0; f < 4; ++f) {
            afr[f] = ld_frag32(smem, db + Abase, f * 16 + lrow, kq16);
            bfr[f] = ld_frag32(smem, db + Bbase, f * 16 + lrow, kq16);
        }
#pragma unroll
        for (int mi = 0; mi < 4; ++mi)
#pragma unroll
            for (int j = 0; j < 4; ++j)
                acc[mi][j] = __builtin_amdgcn_mfma_f32_16x16x32_f16(
                    afr[mi], bfr[j], acc[mi][j], 0, 0, 0);
        __syncthreads();                    // drains vmcnt (stage t+1) + lgkm
    }

#pragma unroll
    for (int j = 0; j < 4; ++j) {
        const int col = n0 + wc * 64 + j * 16 + lrow;
        const float bb = bias ? bias[(long)bz * sBias + col] : 0.f;
#pragma unroll
        for (int mi = 0; mi < 4; ++mi) {
#pragma unroll
            for (int r = 0; r < 4; ++r) {
                const long row = m0 + wr * 64 + mi * 16 + (lane >> 4) * 4 + r;
                const float v = acc[mi][j][r] * scale + bb;
                const long idx = (long)bz * sC + row * (long)N + col;
                if constexpr (OM == 0) ((float*)C)[idx] = v;
                else                   ((unsigned short*)C)[idx] = f2h(v);
            }
        }
    }
}

// ======================= small kernels =======================

// query+keys f32 -> f16, one launch (grid.y selects source)
__global__ __launch_bounds__(256)
void conv2_f16(const float* __restrict__ a, const float* __restrict__ b,
               unsigned short* __restrict__ oa, unsigned short* __restrict__ ob, int n)
{
    int i = (blockIdx.x * 256 + threadIdx.x) * 4;
    if (i >= n) return;
    const float* in = blockIdx.y ? b : a;
    unsigned short* out = blockIdx.y ? ob : oa;
    float4 v = *(const float4*)(in + i);
    s16x4 o = {(short)f2h(v.x), (short)f2h(v.y), (short)f2h(v.z), (short)f2h(v.w)};
    *(s16x4*)(out + i) = o;
}

__global__ __launch_bounds__(256)
void conv_f16(const float* __restrict__ in, unsigned short* __restrict__ out, int n)
{
    int i = (blockIdx.x * 256 + threadIdx.x) * 4;
    if (i >= n) return;
    float4 v = *(const float4*)(in + i);
    s16x4 o = {(short)f2h(v.x), (short)f2h(v.y), (short)f2h(v.z), (short)f2h(v.w)};
    *(s16x4*)(out + i) = o;
}

// [z][1024][1024] f32 -> f16 transpose per z-slice
__global__ __launch_bounds__(256)
void transpose_f16(const float* __restrict__ in, unsigned short* __restrict__ out)
{
    __shared__ float tile[32][33];
    const long base = (long)blockIdx.z * 1024 * 1024;
    const int h0 = blockIdx.x * 32, t0 = blockIdx.y * 32;
    for (int i = threadIdx.y; i < 32; i += 8)
        tile[i][threadIdx.x] = in[base + (long)(t0 + i) * 1024 + h0 + threadIdx.x];
    __syncthreads();
    for (int i = threadIdx.y; i < 32; i += 8)
        out[base + (long)(h0 + i) * 1024 + t0 + threadIdx.x] = f2h(tile[threadIdx.x][i]);
}

// two 1024x1024 transposes in one launch (z=0: Wq->WqT, z=1: Wk->WkT)
__global__ __launch_bounds__(256)
void transpose2_f16(const float* __restrict__ inA, const float* __restrict__ inB,
                    unsigned short* __restrict__ outA, unsigned short* __restrict__ outB)
{
    __shared__ float tile[32][33];
    const float* in = blockIdx.z ? inB : inA;
    unsigned short* out = blockIdx.z ? outB : outA;
    const int h0 = blockIdx.x * 32, t0 = blockIdx.y * 32;
    for (int i = threadIdx.y; i < 32; i += 8)
        tile[i][threadIdx.x] = in[(long)(t0 + i) * 1024 + h0 + threadIdx.x];
    __syncthreads();
    for (int i = threadIdx.y; i < 32; i += 8)
        out[(long)(h0 + i) * 1024 + t0 + threadIdx.x] = f2h(tile[threadIdx.x][i]);
}

// w2[h] = sum_o Wk[o][h] * bq[o]
__global__ __launch_bounds__(256)
void w2_kernel(const float* __restrict__ Wk, const float* __restrict__ bq,
               float* __restrict__ w2)
{
    __shared__ float part[4][64];
    const int tx = threadIdx.x & 63;
    const int ty = threadIdx.x >> 6;
    const int h  = blockIdx.x * 64 + tx;
    float s = 0.f;
    for (int o = ty * 256; o < ty * 256 + 256; ++o)
        s = fmaf(Wk[(long)o * 1024 + h], bq[o], s);
    part[ty][tx] = s;
    __syncthreads();
    if (ty == 0) w2[h] = part[0][tx] + part[1][tx] + part[2][tx] + part[3][tx];
}

// v[r] = sum_h Xk[r][h] * w2[h]
__global__ __launch_bounds__(256)
void matvec_v(const unsigned short* __restrict__ Xk, const float* __restrict__ w2,
              float* __restrict__ v)
{
    const int wave = threadIdx.x >> 6, lane = threadIdx.x & 63;
    const long row = (long)blockIdx.x * 4 + wave;
    const unsigned short* p = Xk + row * 1024 + lane * 16;
    float s = 0.f;
#pragma unroll
    for (int c = 0; c < 2; ++c) {
        s16x8 hv = *(const s16x8*)(p + c * 8);
#pragma unroll
        for (int e = 0; e < 8; ++e)
            s = fmaf(h2f((unsigned short)hv[e]), w2[lane * 16 + c * 8 + e], s);
    }
#pragma unroll
    for (int off = 1; off < 64; off <<= 1) s += __shfl_xor(s, off);
    if (lane == 0) v[row] = s;
}

// MT f16 = sum of 4 f32 partial slabs
__global__ __launch_bounds__(256)
void reduce4(const float* __restrict__ p, unsigned short* __restrict__ MT)
{
    const long i = ((long)blockIdx.x * 256 + threadIdx.x) * 4;
    const long S = 1024L * 1024;
    float4 a = *(const float4*)(p + i);
    float4 b = *(const float4*)(p + S + i);
    float4 c = *(const float4*)(p + 2 * S + i);
    float4 d = *(const float4*)(p + 3 * S + i);
    s16x4 o = {(short)f2h(a.x + b.x + c.x + d.x), (short)f2h(a.y + b.y + c.y + d.y),
               (short)f2h(a.z + b.z + c.z + d.z), (short)f2h(a.w + b.w + c.w + d.w)};
    *(s16x4*)(MT + i) = o;
}

// in-place row softmax on fp16 logits (1024/row)
__global__ __launch_bounds__(256)
void softmax_ip(unsigned short* __restrict__ S)
{
    long row = blockIdx.x;
    const int tid = threadIdx.x;
    s16x4 raw = *(s16x4*)(S + row * 1024 + tid * 4);
    float v0 = h2f((unsigned short)raw[0]), v1 = h2f((unsigned short)raw[1]);
    float v2 = h2f((unsigned short)raw[2]), v3 = h2f((unsigned short)raw[3]);
    float m = fmaxf(fmaxf(v0, v1), fmaxf(v2, v3));
#pragma unroll
    for (int off = 1; off < 64; off <<= 1) m = fmaxf(m, __shfl_xor(m, off));
    __shared__ float redm[4];
    int wave = tid >> 6, lane = tid & 63;
    if (lane == 0) redm[wave] = m;
    __syncthreads();
    m = fmaxf(fmaxf(redm[0], redm[1]), fmaxf(redm[2], redm[3]));

    float e0 = expf(v0 - m), e1 = expf(v1 - m), e2 = expf(v2 - m), e3 = expf(v3 - m);
    float s = e0 + e1 + e2 + e3;
#pragma unroll
    for (int off = 1; off < 64; off <<= 1) s += __shfl_xor(s, off);
    __shared__ float reds[4];
    if (lane == 0) reds[wave] = s;
    __syncthreads();
    s = reds[0] + reds[1] + reds[2] + reds[3];
    float inv = 1.f / s;
    s16x4 o = {(short)f2h(e0 * inv), (short)f2h(e1 * inv),
               (short)f2h(e2 * inv), (short)f2h(e3 * inv)};
    *(s16x4*)(S + row * 1024 + tid * 4) = o;
}

extern "C" void kernel_launch(void* const* d_in, const int* in_sizes, int n_in,
                              void* d_out, int out_size, void* d_ws, size_t ws_size,
                              hipStream_t stream)
{
    const float* query  = (const float*)d_in[0];
    const float* keys   = (const float*)d_in[1];
    const float* values = (const float*)d_in[2];
    const float* Wq     = (const float*)d_in[3];
    const float* bq     = (const float*)d_in[4];
    const float* Wk     = (const float*)d_in[5];
    const float* bk     = (const float*)d_in[6];   // drops out of softmax
    const float* Wo     = (const float*)d_in[7];
    const float* bo     = (const float*)d_in[8];
    (void)bk;

    const int  T = 1024, H = 1024;
    const long NE = 16384L * 1024;
    const long NW = 1024L * 1024;

    size_t need = (size_t)(NE * 4 + NW * 12 + 40960) * sizeof(unsigned short);
    if (ws_size < need) return;

    unsigned short* ws   = (unsigned short*)d_ws;
    unsigned short* Xq   = ws;                 // -> sc after P1
    unsigned short* Xk   = Xq + NE;
    unsigned short* vT   = Xk + NE;
    unsigned short* P1   = vT + NE;            // -> ctx after scores
    unsigned short* WqT  = P1 + NE;
    unsigned short* WkT  = WqT + NW;
    unsigned short* Woh  = WkT + NW;
    unsigned short* MT   = Woh + NW;
    float*          part = (float*)(MT + NW);
    float*          w2   = (float*)(MT + NW * 9);
    float*          vvec = w2 + 1024;
    unsigned short* sc   = Xq;
    unsigned short* ctx  = P1;

    // ---- prep ----
    conv2_f16<<<dim3(16384, 2, 1), 256, 0, stream>>>(query, keys, Xq, Xk, (int)NE);
    transpose2_f16<<<dim3(32, 32, 2), dim3(32, 8), 0, stream>>>(Wq, Wk, WqT, WkT);
    conv_f16<<<1024, 256, 0, stream>>>(Wo, Woh, (int)NW);
    transpose_f16<<<dim3(32, 32, 16), dim3(32, 8), 0, stream>>>(values, vT);
    w2_kernel<<<16, 256, 0, stream>>>(Wk, bq, w2);

    // ---- MT = Wk^T * Wq  (split-K=4 over gemm128 grid 4x8x4 = 128 blocks) ----
    gemm128<0><<<dim3(4, 8, 4), 512, 0, stream>>>(
        WkT, WqT, nullptr, part, 1024, 256, 1024, 256, 256, (long)NW, 0, 1.f);
    reduce4<<<1024, 256, 0, stream>>>(part, MT);

    // ---- P1 = Xq . MT^T  [gemm128 A/B arm: 512 blocks, 2/CU] ----
    gemm128<1><<<dim3(4, 128, 1), 512, 0, stream>>>(
        Xq, MT, nullptr, P1, H, H, H, 0, 0, 0, 0, 1.f);

    // ---- v = Xk . w2 ----
    matvec_v<<<4096, 256, 0, stream>>>(Xk, w2, vvec);

    // ---- scores = P1 . Xk^T + v[s]  [gemm256 control arm] ----
    gemm256<1><<<dim3(4, 4, 16), NTHREADS, 0, stream>>>(
        P1, Xk, vvec, sc, T, H, H,
        (long)T * H, (long)T * H, (long)T * T, (long)T, 1.f);

    // ---- softmax in place ----
    softmax_ip<<<16384, 256, 0, stream>>>(sc);

    // ---- ctx = attn . vT^T / 32  [gemm256 control arm] ----
    gemm256<1><<<dim3(4, 4, 16), NTHREADS, 0, stream>>>(
        sc, vT, nullptr, ctx, H, T, T,
        (long)T * T, (long)T * H, (long)T * H, 0, 1.f / 32.f);

    // ---- out = ctx . Wo^T + bo  [gemm128 A/B arm] ----
    gemm128<0><<<dim3(4, 128, 1), 512, 0, stream>>>(
        ctx, Woh, bo, d_out, H, H, H, 0, 0, 0, 0, 1.f);
}

// Round 10
// 294.041 us; speedup vs baseline: 1.0920x; 1.0207x over previous
//
#include <hip/hip_runtime.h>
#include <math.h>

typedef __attribute__((ext_vector_type(4))) float f32x4;
typedef __attribute__((ext_vector_type(8))) _Float16 h16x8;
typedef __attribute__((ext_vector_type(8))) short s16x8;
typedef __attribute__((ext_vector_type(4))) short s16x4;

__device__ inline unsigned short f2h(float f) {
    union { _Float16 h; unsigned short u; } v; v.h = (_Float16)f; return v.u;
}
__device__ inline float h2f(unsigned short u) {
    union { unsigned short u; _Float16 h; } v; v.u = u; return (float)v.h;
}

__device__ inline void async16(const void* g, void* l) {
    __builtin_amdgcn_global_load_lds(
        (const __attribute__((address_space(1))) unsigned int*)g,
        (__attribute__((address_space(3))) unsigned int*)l, 16, 0, 0);
}

// bijective XCD-aware workgroup swizzle (m204 form)
__device__ inline void xcd_swizzle(int& bx, int& by, int& bz) {
    const long gx = gridDim.x, gy = gridDim.y;
    const long nwg = gx * gy * (long)gridDim.z;
    const long hw  = ((long)blockIdx.z * gy + blockIdx.y) * gx + blockIdx.x;
    const long qq = nwg >> 3, rr = nwg & 7;
    const long xcd = hw & 7, pos = hw >> 3;
    const long lg = (xcd < rr) ? xcd * (qq + 1) + pos
                               : rr * (qq + 1) + (xcd - rr) * qq + pos;
    bx = (int)(lg % gx);
    const long rem = lg / gx;
    by = (int)(rem % gy);
    bz = (int)(rem / gy);
}

// ===== gemm128: 128x256, BK=32, 48 KiB LDS dbuf, ~3 blocks/CU (best measured) =====
#define BM2 128
#define BN2 256
#define BK2 32
// LDS: buf d at d*24576; A (8 KB) at +0; B (16 KB) at +8192.
// 64-B rows, 4 16B slots; swizzle slot ^= row&3 (involution).

__device__ inline h16x8 ld_frag32(const char* smem, unsigned base, int row, int kbyte) {
    unsigned off = base + (unsigned)(row * 64) + (unsigned)(kbyte ^ ((row & 3) << 4));
    return *(const h16x8*)(smem + off);
}

template<int OM>
__global__ __launch_bounds__(512, 4)
void gemm128(const unsigned short* __restrict__ A,
             const unsigned short* __restrict__ B,
             const float* __restrict__ bias,
             void* __restrict__ C, int N, int lenK, int pitch,
             long sA, long sB, long sC, long sBias, float scale)
{
    __shared__ __align__(16) char smem[49152];

    const int tid  = threadIdx.x;
    const int wv   = tid >> 6;
    const int lane = tid & 63;
    const int wr = wv >> 2, wc = wv & 3;       // 2M x 4N waves, 64x64 each
    const int lrow = lane & 15;
    const int kq16 = (lane >> 4) * 16;

    int bx, by, bz; xcd_swizzle(bx, by, bz);
    const int n0 = bx * BN2;
    const int m0 = by * BM2;

    const unsigned short* Ag = A + (long)bz * sA;
    const unsigned short* Bg = B + (long)bz * sB;
    const int NT = lenK / BK2;

    auto stage = [&](int t) {
        const unsigned db = (unsigned)((t & 1) * 24576);
        {
            int r = tid >> 2, s = tid & 3, ss = s ^ (r & 3);
            async16((const char*)Ag + ((long)(m0 + r) * pitch + t * BK2 + ss * 8) * 2,
                    smem + db + (unsigned)(wv << 10));
        }
#pragma unroll
        for (int l = 0; l < 2; ++l) {
            int idx = l * 512 + tid;
            int r = idx >> 2, s = idx & 3, ss = s ^ (r & 3);
            async16((const char*)Bg + ((long)(n0 + r) * pitch + t * BK2 + ss * 8) * 2,
                    smem + db + 8192u + (unsigned)(l * 8192) + (unsigned)(wv << 10));
        }
    };

    f32x4 acc[4][4];
#pragma unroll
    for (int i = 0; i < 4; ++i)
#pragma unroll
        for (int j = 0; j < 4; ++j) acc[i][j] = (f32x4){0.f, 0.f, 0.f, 0.f};

    const unsigned Abase = (unsigned)(wr * 4096);
    const unsigned Bbase = 8192u + (unsigned)(wc * 4096);

    stage(0);
    __syncthreads();

#pragma unroll 2
    for (int t = 0; t < NT; ++t) {
        const unsigned db = (unsigned)((t & 1) * 24576);
        if (t + 1 < NT) stage(t + 1);       // other buffer; safe across 1 barrier
        h16x8 afr[4], bfr[4];
#pragma unroll
        for (int f = 0; f < 4; ++f) {
            afr[f] = ld_frag32(smem, db + Abase, f * 16 + lrow, kq16);
            bfr[f] = ld_frag32(smem, db + Bbase, f * 16 + lrow, kq16);
        }
#pragma unroll
        for (int mi = 0; mi < 4; ++mi)
#pragma unroll
            for (int j = 0; j < 4; ++j)
                acc[mi][j] = __builtin_amdgcn_mfma_f32_16x16x32_f16(
                    afr[mi], bfr[j], acc[mi][j], 0, 0, 0);
        __syncthreads();                    // drains vmcnt (stage t+1) + lgkm
    }

#pragma unroll
    for (int j = 0; j < 4; ++j) {
        const int col = n0 + wc * 64 + j * 16 + lrow;
        const float bb = bias ? bias[(long)bz * sBias + col] : 0.f;
#pragma unroll
        for (int mi = 0; mi < 4; ++mi) {
#pragma unroll
            for (int r = 0; r < 4; ++r) {
                const long row = m0 + wr * 64 + mi * 16 + (lane >> 4) * 4 + r;
                const float v = acc[mi][j][r] * scale + bb;
                const long idx = (long)bz * sC + row * (long)N + col;
                if constexpr (OM == 0) ((float*)C)[idx] = v;
                else                   ((unsigned short*)C)[idx] = f2h(v);
            }
        }
    }
}

// ======================= small kernels =======================

// query+keys f32 -> f16: grid-stride, 16 f32/thread, 4 loads in flight
__global__ __launch_bounds__(256)
void conv2_f16(const float* __restrict__ a, const float* __restrict__ b,
               unsigned short* __restrict__ oa, unsigned short* __restrict__ ob, long n)
{
    const long stride = (long)gridDim.x * 256 * 16;
    const long t0 = ((long)blockIdx.x * 256 + threadIdx.x) * 16;
    for (long i = t0; i < n; i += stride) {
        float4 v0 = *(const float4*)(a + i);
        float4 v1 = *(const float4*)(a + i + 4);
        float4 v2 = *(const float4*)(a + i + 8);
        float4 v3 = *(const float4*)(a + i + 12);
        s16x8 o0 = {(short)f2h(v0.x), (short)f2h(v0.y), (short)f2h(v0.z), (short)f2h(v0.w),
                    (short)f2h(v1.x), (short)f2h(v1.y), (short)f2h(v1.z), (short)f2h(v1.w)};
        s16x8 o1 = {(short)f2h(v2.x), (short)f2h(v2.y), (short)f2h(v2.z), (short)f2h(v2.w),
                    (short)f2h(v3.x), (short)f2h(v3.y), (short)f2h(v3.z), (short)f2h(v3.w)};
        *(s16x8*)(oa + i)     = o0;
        *(s16x8*)(oa + i + 8) = o1;
    }
    for (long i = t0; i < n; i += stride) {
        float4 v0 = *(const float4*)(b + i);
        float4 v1 = *(const float4*)(b + i + 4);
        float4 v2 = *(const float4*)(b + i + 8);
        float4 v3 = *(const float4*)(b + i + 12);
        s16x8 o0 = {(short)f2h(v0.x), (short)f2h(v0.y), (short)f2h(v0.z), (short)f2h(v0.w),
                    (short)f2h(v1.x), (short)f2h(v1.y), (short)f2h(v1.z), (short)f2h(v1.w)};
        s16x8 o1 = {(short)f2h(v2.x), (short)f2h(v2.y), (short)f2h(v2.z), (short)f2h(v2.w),
                    (short)f2h(v3.x), (short)f2h(v3.y), (short)f2h(v3.z), (short)f2h(v3.w)};
        *(s16x8*)(ob + i)     = o0;
        *(s16x8*)(ob + i + 8) = o1;
    }
}

__global__ __launch_bounds__(256)
void conv_f16(const float* __restrict__ in, unsigned short* __restrict__ out, int n)
{
    int i = (blockIdx.x * 256 + threadIdx.x) * 4;
    if (i >= n) return;
    float4 v = *(const float4*)(in + i);
    s16x4 o = {(short)f2h(v.x), (short)f2h(v.y), (short)f2h(v.z), (short)f2h(v.w)};
    *(s16x4*)(out + i) = o;
}

// values [16][1024][1024] f32 -> f16 transpose, grid-stride over z
__global__ __launch_bounds__(256)
void transpose_vals(const float* __restrict__ in, unsigned short* __restrict__ out)
{
    __shared__ float tile[32][33];
    const int h0 = blockIdx.x * 32, t0 = blockIdx.y * 32;
    for (int z = blockIdx.z; z < 16; z += gridDim.z) {
        const long base = (long)z * 1024 * 1024;
        __syncthreads();
        for (int i = threadIdx.y; i < 32; i += 8)
            tile[i][threadIdx.x] = in[base + (long)(t0 + i) * 1024 + h0 + threadIdx.x];
        __syncthreads();
        for (int i = threadIdx.y; i < 32; i += 8)
            out[base + (long)(h0 + i) * 1024 + t0 + threadIdx.x] = f2h(tile[threadIdx.x][i]);
    }
}

// two 1024x1024 transposes in one launch (z=0: Wq->WqT, z=1: Wk->WkT)
__global__ __launch_bounds__(256)
void transpose2_f16(const float* __restrict__ inA, const float* __restrict__ inB,
                    unsigned short* __restrict__ outA, unsigned short* __restrict__ outB)
{
    __shared__ float tile[32][33];
    const float* in = blockIdx.z ? inB : inA;
    unsigned short* out = blockIdx.z ? outB : outA;
    const int h0 = blockIdx.x * 32, t0 = blockIdx.y * 32;
    for (int i = threadIdx.y; i < 32; i += 8)
        tile[i][threadIdx.x] = in[(long)(t0 + i) * 1024 + h0 + threadIdx.x];
    __syncthreads();
    for (int i = threadIdx.y; i < 32; i += 8)
        out[(long)(h0 + i) * 1024 + t0 + threadIdx.x] = f2h(tile[threadIdx.x][i]);
}

// w2[h] = sum_o Wk[o][h] * bq[o]
__global__ __launch_bounds__(256)
void w2_kernel(const float* __restrict__ Wk, const float* __restrict__ bq,
               float* __restrict__ w2)
{
    __shared__ float part[4][64];
    const int tx = threadIdx.x & 63;
    const int ty = threadIdx.x >> 6;
    const int h  = blockIdx.x * 64 + tx;
    float s = 0.f;
    for (int o = ty * 256; o < ty * 256 + 256; ++o)
        s = fmaf(Wk[(long)o * 1024 + h], bq[o], s);
    part[ty][tx] = s;
    __syncthreads();
    if (ty == 0) w2[h] = part[0][tx] + part[1][tx] + part[2][tx] + part[3][tx];
}

// v[r] = sum_h Xk[r][h] * w2[h]
__global__ __launch_bounds__(256)
void matvec_v(const unsigned short* __restrict__ Xk, const float* __restrict__ w2,
              float* __restrict__ v)
{
    const int wave = threadIdx.x >> 6, lane = threadIdx.x & 63;
    const long row = (long)blockIdx.x * 4 + wave;
    const unsigned short* p = Xk + row * 1024 + lane * 16;
    float s = 0.f;
#pragma unroll
    for (int c = 0; c < 2; ++c) {
        s16x8 hv = *(const s16x8*)(p + c * 8);
#pragma unroll
        for (int e = 0; e < 8; ++e)
            s = fmaf(h2f((unsigned short)hv[e]), w2[lane * 16 + c * 8 + e], s);
    }
#pragma unroll
    for (int off = 1; off < 64; off <<= 1) s += __shfl_xor(s, off);
    if (lane == 0) v[row] = s;
}

// MT f16 = sum of 4 f32 partial slabs
__global__ __launch_bounds__(256)
void reduce4(const float* __restrict__ p, unsigned short* __restrict__ MT)
{
    const long i = ((long)blockIdx.x * 256 + threadIdx.x) * 4;
    const long S = 1024L * 1024;
    float4 a = *(const float4*)(p + i);
    float4 b = *(const float4*)(p + S + i);
    float4 c = *(const float4*)(p + 2 * S + i);
    float4 d = *(const float4*)(p + 3 * S + i);
    s16x4 o = {(short)f2h(a.x + b.x + c.x + d.x), (short)f2h(a.y + b.y + c.y + d.y),
               (short)f2h(a.z + b.z + c.z + d.z), (short)f2h(a.w + b.w + c.w + d.w)};
    *(s16x4*)(MT + i) = o;
}

// wave-per-row in-place softmax on fp16 logits (16384 rows x 1024), no LDS
__global__ __launch_bounds__(256)
void softmax_wave(unsigned short* __restrict__ S)
{
    const int wave = threadIdx.x >> 6, lane = threadIdx.x & 63;
    for (long row = (long)blockIdx.x * 4 + wave; row < 16384; row += (long)gridDim.x * 4) {
        unsigned short* p = S + row * 1024;
        s16x8 ra = *(s16x8*)(p + lane * 8);
        s16x8 rb = *(s16x8*)(p + 512 + lane * 8);
        float va[8], vb[8];
        float m = -3.0e38f;
#pragma unroll
        for (int e = 0; e < 8; ++e) {
            va[e] = h2f((unsigned short)ra[e]); m = fmaxf(m, va[e]);
            vb[e] = h2f((unsigned short)rb[e]); m = fmaxf(m, vb[e]);
        }
#pragma unroll
        for (int off = 1; off < 64; off <<= 1) m = fmaxf(m, __shfl_xor(m, off));
        float s = 0.f;
#pragma unroll
        for (int e = 0; e < 8; ++e) {
            va[e] = expf(va[e] - m); s += va[e];
            vb[e] = expf(vb[e] - m); s += vb[e];
        }
#pragma unroll
        for (int off = 1; off < 64; off <<= 1) s += __shfl_xor(s, off);
        const float inv = 1.f / s;
        s16x8 oa, ob;
#pragma unroll
        for (int e = 0; e < 8; ++e) {
            oa[e] = (short)f2h(va[e] * inv);
            ob[e] = (short)f2h(vb[e] * inv);
        }
        *(s16x8*)(p + lane * 8)       = oa;
        *(s16x8*)(p + 512 + lane * 8) = ob;
    }
}

extern "C" void kernel_launch(void* const* d_in, const int* in_sizes, int n_in,
                              void* d_out, int out_size, void* d_ws, size_t ws_size,
                              hipStream_t stream)
{
    const float* query  = (const float*)d_in[0];
    const float* keys   = (const float*)d_in[1];
    const float* values = (const float*)d_in[2];
    const float* Wq     = (const float*)d_in[3];
    const float* bq     = (const float*)d_in[4];
    const float* Wk     = (const float*)d_in[5];
    const float* bk     = (const float*)d_in[6];   // drops out of softmax
    const float* Wo     = (const float*)d_in[7];
    const float* bo     = (const float*)d_in[8];
    (void)bk;

    const int  T = 1024, H = 1024;
    const long NE = 16384L * 1024;
    const long NW = 1024L * 1024;

    size_t need = (size_t)(NE * 4 + NW * 12 + 40960) * sizeof(unsigned short);
    if (ws_size < need) return;

    unsigned short* ws   = (unsigned short*)d_ws;
    unsigned short* Xq   = ws;                 // -> sc after P1
    unsigned short* Xk   = Xq + NE;
    unsigned short* vT   = Xk + NE;
    unsigned short* P1   = vT + NE;            // -> ctx after scores
    unsigned short* WqT  = P1 + NE;
    unsigned short* WkT  = WqT + NW;
    unsigned short* Woh  = WkT + NW;
    unsigned short* MT   = Woh + NW;
    float*          part = (float*)(MT + NW);
    float*          w2   = (float*)(MT + NW * 9);
    float*          vvec = w2 + 1024;
    unsigned short* sc   = Xq;
    unsigned short* ctx  = P1;

    // ---- prep ----
    conv2_f16<<<2048, 256, 0, stream>>>(query, keys, Xq, Xk, NE);
    transpose2_f16<<<dim3(32, 32, 2), dim3(32, 8), 0, stream>>>(Wq, Wk, WqT, WkT);
    conv_f16<<<1024, 256, 0, stream>>>(Wo, Woh, (int)NW);
    transpose_vals<<<dim3(32, 32, 4), dim3(32, 8), 0, stream>>>(values, vT);
    w2_kernel<<<16, 256, 0, stream>>>(Wk, bq, w2);

    // ---- MT = Wk^T * Wq  (split-K=4, grid 4x8x4 = 128 blocks) ----
    gemm128<0><<<dim3(4, 8, 4), 512, 0, stream>>>(
        WkT, WqT, nullptr, part, 1024, 256, 1024, 256, 256, (long)NW, 0, 1.f);
    reduce4<<<1024, 256, 0, stream>>>(part, MT);

    // ---- P1 = Xq . MT^T ----
    gemm128<1><<<dim3(4, 128, 1), 512, 0, stream>>>(
        Xq, MT, nullptr, P1, H, H, H, 0, 0, 0, 0, 1.f);

    // ---- v = Xk . w2 ----
    matvec_v<<<4096, 256, 0, stream>>>(Xk, w2, vvec);

    // ---- scores = P1 . Xk^T + v[s]  (batched) ----
    gemm128<1><<<dim3(4, 8, 16), 512, 0, stream>>>(
        P1, Xk, vvec, sc, T, H, H,
        (long)T * H, (long)T * H, (long)T * T, (long)T, 1.f);

    // ---- softmax in place (wave per row) ----
    softmax_wave<<<2048, 256, 0, stream>>>(sc);

    // ---- ctx = attn . vT^T / 32  (batched) ----
    gemm128<1><<<dim3(4, 8, 16), 512, 0, stream>>>(
        sc, vT, nullptr, ctx, H, T, T,
        (long)T * T, (long)T * H, (long)T * H, 0, 1.f / 32.f);

    // ---- out = ctx . Wo^T + bo ----
    gemm128<0><<<dim3(4, 128, 1), 512, 0, stream>>>(
        ctx, Woh, bo, d_out, H, H, H, 0, 0, 0, 0, 1.f);
}